// Round 5
// baseline (34574.905 us; speedup 1.0000x reference)
//
#include <hip/hip_runtime.h>
#include <float.h>

// Batched transducer greedy decode, B=32 T=1000 H=640 V=5000, fp32.
// Persistent kernel, 240 blocks x 512 thr, 2 grid barriers/step.
// R5: rocprof across R0-R4 shows workspace (d_ws) plain loads are NOT L2-cached
// (residual FETCH == exactly the ws-resident read streams each round), while
// input-buffer reads (Wc) are L2-resident. So R4's repacked-WhP-in-ws re-fetched
// 6.4MB/step at MALL latency inside the GEMM loop. Fix: gate blocks now own 32
// CONTIGUOUS Wh columns (dense 128B lines, read straight from cacheable d_in,
// same as Wc blocks). The 4-gates-per-unit locality is restored via a tiny
// hwh[2560][32] sc1 exchange (80KB/step, one coalesced burst) consumed after
// barrier 1 by 20 "state" blocks that run softmax-combine + LSTM pointwise.
#define BB 32
#define TT 1000
#define HH 640
#define H4 2560
#define VV 5000
#define NLOG 157   // logits tiles, 32 cols each (last tile 8 valid)
#define NGATE 80   // gate GEMM blocks: 32 contiguous Wh cols each
#define NSTATE 20  // state blocks (subset of gate blocks, q<20): 32 units each
#define NB   240   // 8 barrier groups x 30

// workspace layout (float offsets)
#define O_JOINT 0        // jointT[j][b]  (640x32)   cross-block (sc1 path)
#define O_HT    20480    // hT[j][b]      (640x32)   cross-block (sc1 path)
#define O_PM    40960    // partial max    [157*32]  cross-block (sc1 path)
#define O_PS    46080    // partial sumexp [157*32]  cross-block (sc1 path)
#define O_PI    51200    // partial argmax [157*32] (int bits)    (sc1 path)
#define O_BAR   56320    // barrier: 17 slots x 16 u32
#define O_CT    56704    // initial c (640x32) — consumed once at kernel start
#define O_PNT   77184    // initial out_PN (640x32) — consumed once
#define O_HWH   97664    // hwh[c(2560)][b(32)] gate pre-act exchange (sc1 path)
#define O_XWXB  (O_HWH + 81920)   // embed@Wx + b  (5000x2560), optional
#define XWXB_ELEMS ((size_t)VV * (size_t)H4)

typedef unsigned int u32;
typedef unsigned long long u64;

__device__ __forceinline__ float sigf(float x) { return 1.0f / (1.0f + expf(-x)); }

// ---- sc1 (MALL-coherent) scalar access helpers.
__device__ __forceinline__ float ldc1(const float* p) {
  u32 v = __hip_atomic_load((const u32*)p, __ATOMIC_RELAXED, __HIP_MEMORY_SCOPE_AGENT);
  return __uint_as_float(v);
}
__device__ __forceinline__ void stc1(float* p, float x) {
  __hip_atomic_store((u32*)p, __float_as_uint(x), __ATOMIC_RELAXED, __HIP_MEMORY_SCOPE_AGENT);
}
// two sc1 float4 loads, issued back-to-back, one latency shot
__device__ __forceinline__ void ldc4x2(float4* a, float4* b, const float* pa, const float* pb) {
  asm volatile(
      "global_load_dwordx4 %0, %2, off sc0 sc1\n\t"
      "global_load_dwordx4 %1, %3, off sc0 sc1\n\t"
      "s_waitcnt vmcnt(0)"
      : "=&v"(*a), "=&v"(*b) : "v"(pa), "v"(pb) : "memory");
}

// ---- staged sc1 burst: 20480 floats global -> LDS, 512 threads, 10 dwordx4
// ---- per thread, ONE vmcnt wait (one MALL latency shot).
__device__ __forceinline__ void stage_sc1_full(float* dst, const float* src, int tid) {
  const float* p0 = src + 4 * (tid + 0 * 512);
  const float* p1 = src + 4 * (tid + 1 * 512);
  const float* p2 = src + 4 * (tid + 2 * 512);
  const float* p3 = src + 4 * (tid + 3 * 512);
  const float* p4 = src + 4 * (tid + 4 * 512);
  const float* p5 = src + 4 * (tid + 5 * 512);
  const float* p6 = src + 4 * (tid + 6 * 512);
  const float* p7 = src + 4 * (tid + 7 * 512);
  const float* p8 = src + 4 * (tid + 8 * 512);
  const float* p9 = src + 4 * (tid + 9 * 512);
  float4 a0, a1, a2, a3, a4, a5, a6, a7, a8, a9;
  asm volatile(
      "global_load_dwordx4 %0, %10, off sc0 sc1\n\t"
      "global_load_dwordx4 %1, %11, off sc0 sc1\n\t"
      "global_load_dwordx4 %2, %12, off sc0 sc1\n\t"
      "global_load_dwordx4 %3, %13, off sc0 sc1\n\t"
      "global_load_dwordx4 %4, %14, off sc0 sc1\n\t"
      "global_load_dwordx4 %5, %15, off sc0 sc1\n\t"
      "global_load_dwordx4 %6, %16, off sc0 sc1\n\t"
      "global_load_dwordx4 %7, %17, off sc0 sc1\n\t"
      "global_load_dwordx4 %8, %18, off sc0 sc1\n\t"
      "global_load_dwordx4 %9, %19, off sc0 sc1\n\t"
      "s_waitcnt vmcnt(0)"
      : "=&v"(a0), "=&v"(a1), "=&v"(a2), "=&v"(a3), "=&v"(a4),
        "=&v"(a5), "=&v"(a6), "=&v"(a7), "=&v"(a8), "=&v"(a9)
      : "v"(p0), "v"(p1), "v"(p2), "v"(p3), "v"(p4),
        "v"(p5), "v"(p6), "v"(p7), "v"(p8), "v"(p9)
      : "memory");
  float4* d4 = (float4*)dst;
  d4[tid + 0 * 512] = a0;
  d4[tid + 1 * 512] = a1;
  d4[tid + 2 * 512] = a2;
  d4[tid + 3 * 512] = a3;
  d4[tid + 4 * 512] = a4;
  d4[tid + 5 * 512] = a5;
  d4[tid + 6 * 512] = a6;
  d4[tid + 7 * 512] = a7;
  d4[tid + 8 * 512] = a8;
  d4[tid + 9 * 512] = a9;
}

// grid barrier: fence-free (all cross-block data flows through sc1/MALL).
__device__ __forceinline__ void grid_bar(unsigned* bar, unsigned target) {
  __syncthreads();
  if (threadIdx.x == 0) {
    const int g = (int)blockIdx.x / 30;
    unsigned* cnt  = bar + g * 16;
    unsigned* gen  = bar + (9 + g) * 16;
    asm volatile("s_waitcnt vmcnt(0)" ::: "memory");
    unsigned a = __hip_atomic_fetch_add(cnt, 1u, __ATOMIC_RELAXED, __HIP_MEMORY_SCOPE_AGENT);
    if (a == 29u) {
      unsigned* root = bar + 8 * 16;
      unsigned r = __hip_atomic_fetch_add(root, 1u, __ATOMIC_RELAXED, __HIP_MEMORY_SCOPE_AGENT);
      if (r == 7u) {
        __hip_atomic_store(root, 0u, __ATOMIC_RELAXED, __HIP_MEMORY_SCOPE_AGENT);
#pragma unroll
        for (int i = 0; i < 8; ++i)
          __hip_atomic_store(bar + i * 16, 0u, __ATOMIC_RELAXED, __HIP_MEMORY_SCOPE_AGENT);
        asm volatile("s_waitcnt vmcnt(0)" ::: "memory");
#pragma unroll
        for (int i = 0; i < 8; ++i)
          __hip_atomic_store(bar + (9 + i) * 16, target, __ATOMIC_RELEASE, __HIP_MEMORY_SCOPE_AGENT);
      }
    }
    while (__hip_atomic_load(gen, __ATOMIC_RELAXED, __HIP_MEMORY_SCOPE_AGENT) < target)
      __builtin_amdgcn_s_sleep(1);
  }
  __syncthreads();
}

// ---------------- precompute: xwxb[v][c] = sum_k embed[v][k]*Wx[k][c] + b[c]
__global__ __launch_bounds__(256) void precompute_k(const float* __restrict__ embed,
                                                    const float* __restrict__ Wx,
                                                    const float* __restrict__ bias,
                                                    float* __restrict__ xwxb) {
  __shared__ float embT[HH * 17];
  const int tid = threadIdx.x;
  const int v0 = blockIdx.y * 16;
  const int c0 = blockIdx.x * 256 + (tid & 63) * 4;
  const int vg = tid >> 6;
  for (int i = tid; i < 16 * 160; i += 256) {
    int vr = i / 160, kq = i - vr * 160;
    int v = v0 + vr; if (v >= VV) v = VV - 1;
    float4 e = *(const float4*)&embed[(size_t)v * HH + kq * 4];
    embT[(kq * 4 + 0) * 17 + vr] = e.x;
    embT[(kq * 4 + 1) * 17 + vr] = e.y;
    embT[(kq * 4 + 2) * 17 + vr] = e.z;
    embT[(kq * 4 + 3) * 17 + vr] = e.w;
  }
  __syncthreads();
  float acc[16];
#pragma unroll
  for (int i = 0; i < 16; ++i) acc[i] = 0.f;
#pragma unroll 4
  for (int k = 0; k < HH; ++k) {
    float4 wv = *(const float4*)&Wx[(size_t)k * H4 + c0];
#pragma unroll
    for (int i = 0; i < 4; ++i) {
      float e = embT[k * 17 + vg * 4 + i];
      acc[i * 4 + 0] += e * wv.x;
      acc[i * 4 + 1] += e * wv.y;
      acc[i * 4 + 2] += e * wv.z;
      acc[i * 4 + 3] += e * wv.w;
    }
  }
  float4 bv = *(const float4*)&bias[c0];
#pragma unroll
  for (int i = 0; i < 4; ++i) {
    int v = v0 + vg * 4 + i;
    if (v < VV) {
      float4 r;
      r.x = acc[i * 4 + 0] + bv.x; r.y = acc[i * 4 + 1] + bv.y;
      r.z = acc[i * 4 + 2] + bv.z; r.w = acc[i * 4 + 3] + bv.w;
      *(float4*)&xwxb[(size_t)v * H4 + c0] = r;
    }
  }
}

// ---------------- init: barrier zero + initial LSTM step (h0=c0=0, tok=0) + joint t=0
__global__ __launch_bounds__(256) void init_k(const float* __restrict__ tn,
                                              const float* __restrict__ embed,
                                              const float* __restrict__ Wx,
                                              const float* __restrict__ bias,
                                              float* ws, int use_table) {
  const int tid = threadIdx.x, bid = blockIdx.x;
  const int b = tid & 31, c8 = tid >> 5;
  const int j = bid * 8 + c8;
  if (bid == 0) {
    unsigned* bar = (unsigned*)(ws + O_BAR);
    for (int i = tid; i < 17 * 16; i += 256) bar[i] = 0u;
  }
  const float* xwxb = ws + O_XWXB;
  float g4[4];
  if (use_table) {
#pragma unroll
    for (int g = 0; g < 4; ++g) g4[g] = xwxb[g * HH + j];  // token 0 row
  } else {
#pragma unroll
    for (int g = 0; g < 4; ++g) g4[g] = bias[g * HH + j];
#pragma unroll 4
    for (int k = 0; k < HH; ++k) {
      float xv = embed[k];  // token 0 row
#pragma unroll
      for (int g = 0; g < 4; ++g) g4[g] += xv * Wx[(size_t)k * H4 + g * HH + j];
    }
  }
  float c1 = sigf(g4[0]) * tanhf(g4[2]);
  float h1 = sigf(g4[3]) * tanhf(c1);
  ws[O_CT + j * 32 + b] = c1;
  ws[O_HT + j * 32 + b] = h1;
  ws[O_PNT + j * 32 + b] = h1;
  ws[O_JOINT + j * 32 + b] = tanhf(tn[(size_t)b * TT * HH + j] + h1);
}

// ---------------- persistent decode kernel
__global__ __launch_bounds__(512) void decode_k(const float* __restrict__ tn,
                                                const float* __restrict__ embed,
                                                const float* __restrict__ Wx,
                                                const float* __restrict__ bias,
                                                const float* __restrict__ Wh,
                                                const float* __restrict__ Wc,
                                                const float* __restrict__ bc,
                                                float* __restrict__ out,
                                                float* ws, int use_table) {
  __shared__ float joint_s[20480];  // 80 KB: full 640x32 joint/h tile (per step)
  __shared__ float smem[11008];     // overlay: A: part[8][1152]+lm/lsv/lix; B: rm/rs/ri+gmat+xl
  __shared__ float c_s[1024];       // state: c   [32 units][32 b]
  __shared__ float pn_s[1024];      // state: out_PN
  __shared__ int s_tok[32];
  __shared__ int s_upd[32];
  __shared__ int s_ptok[32];
  __shared__ float s_scores[32];
  const int tid = threadIdx.x, bid = blockIdx.x;
  unsigned* bar = (unsigned*)(ws + O_BAR);
  const float* xwxb = ws + O_XWXB;
  const bool is_log = (bid < NLOG);
  const bool is_gate = (bid >= NLOG) && (bid < NLOG + NGATE);
  const int q = bid - NLOG;                    // gate col-block index [0,80)
  const bool is_state = is_gate && (q < NSTATE);  // owns units [32q,32q+32)

  if (tid < 32) { s_ptok[tid] = 0; s_scores[tid] = 0.f; }
  if (is_state) {
    const int b = tid & 31, uu = tid >> 5;
    c_s[uu * 32 + b] = ws[O_CT + (size_t)(32 * q + uu) * 32 + b];
    c_s[(uu + 16) * 32 + b] = ws[O_CT + (size_t)(32 * q + uu + 16) * 32 + b];
    pn_s[uu * 32 + b] = ws[O_PNT + (size_t)(32 * q + uu) * 32 + b];
    pn_s[(uu + 16) * 32 + b] = ws[O_PNT + (size_t)(32 * q + uu + 16) * 32 + b];
  }
  __syncthreads();

  // ---- GEMM thread decomposition: 8 cols x 4 batches per thread, 16-way K split
  const int lane = tid & 63, wvv = tid >> 6;
  const int sub = lane >> 5;          // K-split parity
  const int cg  = lane & 3;           // 4 col-groups of 8 contiguous cols
  const int bg  = (lane >> 2) & 7;    // 8 batch-groups of 4
  const int kb  = (wvv * 2 + sub) * 40;  // this thread's 40-row K chunk
  // weight base (cacheable d_in, dense 128B lines) + row stride
  const float* wbase;
  int wstride;
  if (is_log) {
    int c = bid * 32 + cg * 8;
    if (c > VV - 8) c = VV - 8;   // clamp (dup cols; masked at logits stage)
    wbase = Wc + (size_t)kb * VV + c;
    wstride = VV;
  } else {
    wbase = Wh + (size_t)kb * H4 + q * 32 + cg * 8;  // contiguous cols [32q,32q+32)
    wstride = H4;
  }
  const float* jb0 = joint_s + kb * 32 + bg * 4;

  unsigned epoch = 0;
  for (int t = 0; t < TT; ++t) {
    float tnv0 = 0.f, tnv1 = 0.f;  // state: tn[b][t+1][32q+uu], held across barrier 1

    // ================= phase A =================
    if (is_log || is_gate) {
      if (is_state && t + 1 < TT) {
        const int b = tid & 31, uu = tid >> 5;
        tnv0 = tn[((size_t)b * TT + (t + 1)) * HH + 32 * q + uu];
        tnv1 = tn[((size_t)b * TT + (t + 1)) * HH + 32 * q + uu + 16];
      }
      // stage the full 640x32 tile: one sc1 burst, one latency shot
      stage_sc1_full(joint_s, ws + (is_log ? O_JOINT : O_HT), tid);
      __syncthreads();

      float acc[32];  // acc[c*4+b]: 8 cols x 4 batches
#pragma unroll
      for (int i = 0; i < 32; ++i) acc[i] = 0.f;
      {
        const float* wp = wbase;
        const float* jp = jb0;
#pragma unroll 4
        for (int kk = 0; kk < 40; ++kk) {
          float4 w0 = *(const float4*)(wp);
          float4 w1 = *(const float4*)(wp + 4);
          float4 jv = *(const float4*)(jp);
          wp += wstride;
          jp += 32;
          acc[0]  += w0.x * jv.x; acc[1]  += w0.x * jv.y; acc[2]  += w0.x * jv.z; acc[3]  += w0.x * jv.w;
          acc[4]  += w0.y * jv.x; acc[5]  += w0.y * jv.y; acc[6]  += w0.y * jv.z; acc[7]  += w0.y * jv.w;
          acc[8]  += w0.z * jv.x; acc[9]  += w0.z * jv.y; acc[10] += w0.z * jv.z; acc[11] += w0.z * jv.w;
          acc[12] += w0.w * jv.x; acc[13] += w0.w * jv.y; acc[14] += w0.w * jv.z; acc[15] += w0.w * jv.w;
          acc[16] += w1.x * jv.x; acc[17] += w1.x * jv.y; acc[18] += w1.x * jv.z; acc[19] += w1.x * jv.w;
          acc[20] += w1.y * jv.x; acc[21] += w1.y * jv.y; acc[22] += w1.y * jv.z; acc[23] += w1.y * jv.w;
          acc[24] += w1.z * jv.x; acc[25] += w1.z * jv.y; acc[26] += w1.z * jv.z; acc[27] += w1.z * jv.w;
          acc[28] += w1.w * jv.x; acc[29] += w1.w * jv.y; acc[30] += w1.w * jv.z; acc[31] += w1.w * jv.w;
        }
      }
#pragma unroll
      for (int i = 0; i < 32; ++i) acc[i] += __shfl_xor(acc[i], 32);
      float* part = smem;  // [8 waves][32 cols * 36]
      if (sub == 0) {
        float* pb = part + wvv * 1152 + bg * 4;
#pragma unroll
        for (int c = 0; c < 8; ++c)
          *(float4*)&pb[(cg * 8 + c) * 36] =
              make_float4(acc[c * 4 + 0], acc[c * 4 + 1], acc[c * 4 + 2], acc[c * 4 + 3]);
      }
      __syncthreads();

      const int b = tid & 31, colg = tid >> 5;
      if (is_log) {
        float* lm = smem + 9216;
        float* lsv = smem + 9744;
        int* lix = (int*)(smem + 10272);
        float m = -FLT_MAX; int ix = 0;
        float lv[2];
#pragma unroll
        for (int i = 0; i < 2; ++i) {
          const int cl = colg * 2 + i;
          float s = 0.f;
#pragma unroll
          for (int qq = 0; qq < 8; ++qq) s += part[qq * 1152 + cl * 36 + b];
          int cgl = bid * 32 + cl;
          float l = (cgl < VV) ? s + bc[cgl] : -FLT_MAX;
          lv[i] = l;
          if (l > m) { m = l; ix = cgl; }
        }
        float e = 0.f;
        if (m > -FLT_MAX) {
#pragma unroll
          for (int i = 0; i < 2; ++i) e += expf(lv[i] - m);
        }
        lm[colg * 33 + b] = m; lsv[colg * 33 + b] = e; lix[colg * 33 + b] = ix;
        __syncthreads();
        if (tid < 32) {
          float m2 = lm[tid], s2 = lsv[tid]; int ix2 = lix[tid];
#pragma unroll
          for (int qq = 1; qq < 16; ++qq) {
            float M = lm[qq * 33 + tid], S = lsv[qq * 33 + tid]; int I = lix[qq * 33 + tid];
            if (M > m2) { s2 = s2 * expf(m2 - M) + S; m2 = M; ix2 = I; }
            else if (M > -FLT_MAX) { s2 += S * expf(M - m2); }
          }
          stc1(&ws[O_PM + bid * 32 + tid], m2);
          stc1(&ws[O_PS + bid * 32 + tid], s2);
          stc1(&ws[O_PI + bid * 32 + tid], __int_as_float(ix2));
        }
      } else {
        // gate: publish hwh for global cols 32q + cl  (sc1 exchange)
#pragma unroll
        for (int i = 0; i < 2; ++i) {
          const int cl = colg * 2 + i;
          float s = 0.f;
#pragma unroll
          for (int qq = 0; qq < 8; ++qq) s += part[qq * 1152 + cl * 36 + b];
          stc1(&ws[O_HWH + (size_t)(q * 32 + cl) * 32 + b], s);
        }
      }
    }
    epoch++;
    grid_bar(bar, epoch);  // state blocks read partials + hwh next

    // ================= phase B (state blocks only) =================
    if (is_state) {
      float* rm = smem;               // [16*33]
      float* rs = smem + 528;
      int* ri = (int*)(smem + 1056);
      float* gmat = smem + 1584;      // [4 gates][32 units][32 b], idx (tg*32+uu)*33+tg+b
      float* xl = smem + 5824;        // [32*161] fallback staging
      const int r = tid & 31, c16 = tid >> 5;
      {
        float m = -FLT_MAX, s = 0.f; int ix = 0;
#pragma unroll
        for (int i = 0; i < 10; ++i) {
          int idx = c16 * 10 + i;
          bool v = (idx < NLOG);
          int ic = v ? idx : 0;
          float M = ldc1(&ws[O_PM + ic * 32 + r]);
          float S = ldc1(&ws[O_PS + ic * 32 + r]);
          int I = __float_as_int(ldc1(&ws[O_PI + ic * 32 + r]));
          if (!v) { M = -FLT_MAX; S = 0.f; I = 0; }
          if (M > m) { s = s * expf(m - M) + S; m = M; ix = I; }
          else if (M > -FLT_MAX) { s += S * expf(M - m); }
        }
        rm[c16 * 33 + r] = m; rs[c16 * 33 + r] = s; ri[c16 * 33 + r] = ix;
      }
      __syncthreads();
      if (tid < 32) {
        float m = rm[tid], s = rs[tid]; int ix = ri[tid];
#pragma unroll
        for (int qq = 1; qq < 16; ++qq) {
          float M = rm[qq * 33 + tid], S = rs[qq * 33 + tid]; int I = ri[qq * 33 + tid];
          if (M > m) { s = s * expf(m - M) + S; m = M; ix = I; }
          else { s += S * expf(M - m); }
        }
        int pos = ix;
        int upd = (pos != 0) ? 1 : 0;
        int ntk = upd ? pos : s_ptok[tid];
        s_tok[tid] = ntk; s_upd[tid] = upd; s_ptok[tid] = ntk;
        if (bid == NLOG) {  // emitter (state block q=0)
          float sc = s_scores[tid];
          if (upd) sc -= logf(s);
          s_scores[tid] = sc;
          out[BB + (size_t)tid * TT + t] = upd ? (float)pos : 0.0f;
          if (t == TT - 1) out[tid] = sc;
        }
      }
      __syncthreads();

      // gather hwh (4 contiguous 4KB chunks) — one sc1 burst
      float4 hv0, hv1;
      {
        int idx0 = tid, idx1 = tid + 512;  // [0,1024) float4-index space
        int tg0 = idx0 >> 8, w40 = idx0 & 255;
        int tg1 = idx1 >> 8, w41 = idx1 & 255;
        const float* pa = ws + O_HWH + ((size_t)tg0 * HH + 32 * q) * 32 + w40 * 4;
        const float* pb = ws + O_HWH + ((size_t)tg1 * HH + 32 * q) * 32 + w41 * 4;
        ldc4x2(&hv0, &hv1, pa, pb);
        // write gmat = hwh (+bias if no table)
#pragma unroll
        for (int p = 0; p < 2; ++p) {
          int tg = p ? tg1 : tg0, w4 = p ? w41 : w40;
          float4 v = p ? hv1 : hv0;
          int uu = w4 >> 3, b0 = (w4 & 7) * 4;
          float bs = use_table ? 0.f : bias[tg * HH + 32 * q + uu];
          int gb = (tg * 32 + uu) * 33 + tg + b0;
          gmat[gb + 0] = v.x + bs; gmat[gb + 1] = v.y + bs;
          gmat[gb + 2] = v.z + bs; gmat[gb + 3] = v.w + bs;
        }
      }
      __syncthreads();
      if (use_table) {
        // add xwxb[tok[b]] rows (uncached ws -> MALL; coalesced float4)
#pragma unroll
        for (int p = 0; p < 2; ++p) {
          int idx = p * 512 + tid;
          int b = idx >> 5, tg = (idx >> 3) & 3, f4 = idx & 7;
          float4 x = *(const float4*)&xwxb[(size_t)s_tok[b] * H4 + tg * HH + 32 * q + f4 * 4];
          int base = (tg * 32 + f4 * 4) * 33 + tg + b;
          gmat[base + 0 * 33] += x.x;
          gmat[base + 1 * 33] += x.y;
          gmat[base + 2 * 33] += x.z;
          gmat[base + 3 * 33] += x.w;
        }
        __syncthreads();
      }
      float gv0[4] = {0.f, 0.f, 0.f, 0.f}, gv1[4] = {0.f, 0.f, 0.f, 0.f};
      if (!use_table) {
        const int b = tid & 31, uu0 = tid >> 5;
        for (int st = 0; st < 4; ++st) {
          const int k0 = st * 160;
          __syncthreads();
          for (int i = tid; i < 32 * 160; i += 512) {
            int bb = i / 160, kk = i - bb * 160;
            xl[bb * 161 + kk] = embed[(size_t)s_tok[bb] * HH + k0 + kk];
          }
          __syncthreads();
          for (int k = 0; k < 160; ++k) {
            float xv = xl[b * 161 + k];
            const float* wxr = Wx + (size_t)(k0 + k) * H4 + 32 * q;
#pragma unroll
            for (int tg = 0; tg < 4; ++tg) {
              gv0[tg] += xv * wxr[tg * HH + uu0];
              gv1[tg] += xv * wxr[tg * HH + uu0 + 16];
            }
          }
        }
        __syncthreads();
      }
      // pointwise LSTM for units [32q,32q+32) x 32 b  (2 per thread)
      {
        const int b = tid & 31;
#pragma unroll
        for (int p = 0; p < 2; ++p) {
          const int uu = (tid >> 5) + p * 16;
          const float* gvx = p ? gv1 : gv0;
          float gi = gmat[(0 * 32 + uu) * 33 + 0 + b] + gvx[0];
          float gf = gmat[(1 * 32 + uu) * 33 + 1 + b] + gvx[1];
          float gg = gmat[(2 * 32 + uu) * 33 + 2 + b] + gvx[2];
          float go = gmat[(3 * 32 + uu) * 33 + 3 + b] + gvx[3];
          float cold = c_s[uu * 32 + b];
          float c2 = sigf(gf) * cold + sigf(gi) * tanhf(gg);
          float h2 = sigf(go) * tanhf(c2);
          float pv;
          if (s_upd[b]) {
            c_s[uu * 32 + b] = c2;
            pn_s[uu * 32 + b] = h2;
            stc1(&ws[O_HT + (size_t)(32 * q + uu) * 32 + b], h2);
            pv = h2;
          } else {
            pv = pn_s[uu * 32 + b];
          }
          if (t + 1 < TT) {
            float tv = p ? tnv1 : tnv0;
            stc1(&ws[O_JOINT + (size_t)(32 * q + uu) * 32 + b], tanhf(tv + pv));
          }
        }
      }
    }
    epoch++;
    grid_bar(bar, epoch);  // next A stages jointT / hT
  }
}

extern "C" void kernel_launch(void* const* d_in, const int* in_sizes, int n_in,
                              void* d_out, int out_size, void* d_ws, size_t ws_size,
                              hipStream_t stream) {
  const float* tn    = (const float*)d_in[0];
  const float* embed = (const float*)d_in[1];
  const float* Wx    = (const float*)d_in[2];
  const float* Wh    = (const float*)d_in[3];
  const float* bias  = (const float*)d_in[4];
  const float* Wc    = (const float*)d_in[5];
  const float* bc    = (const float*)d_in[6];
  float* out = (float*)d_out;
  float* ws  = (float*)d_ws;

  const size_t need_table = (size_t)(O_XWXB + XWXB_ELEMS) * sizeof(float);
  const int use_table = (ws_size >= need_table) ? 1 : 0;

  if (use_table)
    hipLaunchKernelGGL(precompute_k, dim3(10, 313), dim3(256), 0, stream,
                       embed, Wx, bias, ws + O_XWXB);
  hipLaunchKernelGGL(init_k, dim3(80), dim3(256), 0, stream, tn, embed, Wx, bias, ws, use_table);
  hipLaunchKernelGGL(decode_k, dim3(NB), dim3(512), 0, stream,
                     tn, embed, Wx, bias, Wh, Wc, bc, out, ws, use_table);
}

// Round 6
// 30354.211 us; speedup vs baseline: 1.1390x; 1.1390x over previous
//
#include <hip/hip_runtime.h>
#include <float.h>

// Batched transducer greedy decode, B=32 T=1000 H=640 V=5000, fp32.
// Persistent kernel, 240 blocks x 512 thr, 2 grid barriers/step.
// R6: weight residency, final resolution from R3-R5 counter evidence:
//  - ws (d_ws) is fine-grained => NEVER L2-cached (R4: WhP re-fetch 6.4MB/step).
//  - Wh from d_in thrashes L2: row stride 10240B = exactly 80 lines => all rows
//    of a block map to sets == q (mod 16); ~10 co-resident gate blocks/XCD
//    => ~25 lines/set >> 16-way assoc (R5: FETCH unchanged, regressed).
//  - Wc from d_in DOES cache (stride 20000B not line-aligned => set-scrambled).
// So: gate weights staged ONCE into 80KB LDS (one-time cost), GEMM reads them
// as 2x ds_read_b128; logits keep Wc direct from d_in (R4 path, proven).
// Gate blocks stage hT in two 40KB halves (LDS budget); logits stage the full
// 80KB jointT. Phase B reverts to R4's block-local form (no hwh exchange).
// Barrier: R4's all-RELAXED fence-free form (R5's RELEASE added maintenance).
#define BB 32
#define TT 1000
#define HH 640
#define H4 2560
#define VV 5000
#define NLOG 157   // logits tiles, 32 cols each (last tile 8 valid)
#define NGATE 80   // gate blocks: 8 units x 4 gates each, weights in LDS
#define NB   240   // 8 barrier groups x 30

// workspace layout (float offsets)
#define O_JOINT 0        // jointT[j][b]  (640x32)   cross-block (sc1 path)
#define O_HT    20480    // hT[j][b]      (640x32)   cross-block (sc1 path)
#define O_PM    40960    // partial max    [157*32]  cross-block (sc1 path)
#define O_PS    46080    // partial sumexp [157*32]  cross-block (sc1 path)
#define O_PI    51200    // partial argmax [157*32] (int bits)    (sc1 path)
#define O_BAR   56320    // barrier: 17 slots x 16 u32
#define O_CT    56704    // initial c (640x32) — consumed once at kernel start
#define O_PNT   77184    // initial out_PN (640x32) — consumed once
#define O_XWXB  97664    // embed@Wx + b  (5000x2560), optional
#define XWXB_ELEMS ((size_t)VV * (size_t)H4)

typedef unsigned int u32;
typedef unsigned long long u64;

__device__ __forceinline__ float sigf(float x) { return 1.0f / (1.0f + expf(-x)); }

// ---- sc1 (MALL-coherent) scalar access helpers.
__device__ __forceinline__ float ldc1(const float* p) {
  u32 v = __hip_atomic_load((const u32*)p, __ATOMIC_RELAXED, __HIP_MEMORY_SCOPE_AGENT);
  return __uint_as_float(v);
}
__device__ __forceinline__ void stc1(float* p, float x) {
  __hip_atomic_store((u32*)p, __float_as_uint(x), __ATOMIC_RELAXED, __HIP_MEMORY_SCOPE_AGENT);
}

// ---- sc1 burst: 10240 floats global -> LDS, 512 thr, 5 dwordx4/thread, one vmcnt.
__device__ __forceinline__ void stage_sc1_half(float* dst, const float* src, int tid) {
  const float* p0 = src + 4 * (tid + 0 * 512);
  const float* p1 = src + 4 * (tid + 1 * 512);
  const float* p2 = src + 4 * (tid + 2 * 512);
  const float* p3 = src + 4 * (tid + 3 * 512);
  const float* p4 = src + 4 * (tid + 4 * 512);
  float4 a0, a1, a2, a3, a4;
  asm volatile(
      "global_load_dwordx4 %0, %5, off sc0 sc1\n\t"
      "global_load_dwordx4 %1, %6, off sc0 sc1\n\t"
      "global_load_dwordx4 %2, %7, off sc0 sc1\n\t"
      "global_load_dwordx4 %3, %8, off sc0 sc1\n\t"
      "global_load_dwordx4 %4, %9, off sc0 sc1\n\t"
      "s_waitcnt vmcnt(0)"
      : "=&v"(a0), "=&v"(a1), "=&v"(a2), "=&v"(a3), "=&v"(a4)
      : "v"(p0), "v"(p1), "v"(p2), "v"(p3), "v"(p4)
      : "memory");
  float4* d4 = (float4*)dst;
  d4[tid + 0 * 512] = a0;
  d4[tid + 1 * 512] = a1;
  d4[tid + 2 * 512] = a2;
  d4[tid + 3 * 512] = a3;
  d4[tid + 4 * 512] = a4;
}

// ---- sc1 burst: 20480 floats global -> LDS, 10 dwordx4/thread, one vmcnt.
__device__ __forceinline__ void stage_sc1_full(float* dst, const float* src, int tid) {
  const float* p0 = src + 4 * (tid + 0 * 512);
  const float* p1 = src + 4 * (tid + 1 * 512);
  const float* p2 = src + 4 * (tid + 2 * 512);
  const float* p3 = src + 4 * (tid + 3 * 512);
  const float* p4 = src + 4 * (tid + 4 * 512);
  const float* p5 = src + 4 * (tid + 5 * 512);
  const float* p6 = src + 4 * (tid + 6 * 512);
  const float* p7 = src + 4 * (tid + 7 * 512);
  const float* p8 = src + 4 * (tid + 8 * 512);
  const float* p9 = src + 4 * (tid + 9 * 512);
  float4 a0, a1, a2, a3, a4, a5, a6, a7, a8, a9;
  asm volatile(
      "global_load_dwordx4 %0, %10, off sc0 sc1\n\t"
      "global_load_dwordx4 %1, %11, off sc0 sc1\n\t"
      "global_load_dwordx4 %2, %12, off sc0 sc1\n\t"
      "global_load_dwordx4 %3, %13, off sc0 sc1\n\t"
      "global_load_dwordx4 %4, %14, off sc0 sc1\n\t"
      "global_load_dwordx4 %5, %15, off sc0 sc1\n\t"
      "global_load_dwordx4 %6, %16, off sc0 sc1\n\t"
      "global_load_dwordx4 %7, %17, off sc0 sc1\n\t"
      "global_load_dwordx4 %8, %18, off sc0 sc1\n\t"
      "global_load_dwordx4 %9, %19, off sc0 sc1\n\t"
      "s_waitcnt vmcnt(0)"
      : "=&v"(a0), "=&v"(a1), "=&v"(a2), "=&v"(a3), "=&v"(a4),
        "=&v"(a5), "=&v"(a6), "=&v"(a7), "=&v"(a8), "=&v"(a9)
      : "v"(p0), "v"(p1), "v"(p2), "v"(p3), "v"(p4),
        "v"(p5), "v"(p6), "v"(p7), "v"(p8), "v"(p9)
      : "memory");
  float4* d4 = (float4*)dst;
  d4[tid + 0 * 512] = a0;
  d4[tid + 1 * 512] = a1;
  d4[tid + 2 * 512] = a2;
  d4[tid + 3 * 512] = a3;
  d4[tid + 4 * 512] = a4;
  d4[tid + 5 * 512] = a5;
  d4[tid + 6 * 512] = a6;
  d4[tid + 7 * 512] = a7;
  d4[tid + 8 * 512] = a8;
  d4[tid + 9 * 512] = a9;
}

// grid barrier: fence-free (all cross-block data flows through sc1/MALL).
__device__ __forceinline__ void grid_bar(unsigned* bar, unsigned target) {
  __syncthreads();
  if (threadIdx.x == 0) {
    const int g = (int)blockIdx.x / 30;
    unsigned* cnt  = bar + g * 16;
    unsigned* gen  = bar + (9 + g) * 16;
    asm volatile("s_waitcnt vmcnt(0)" ::: "memory");
    unsigned a = __hip_atomic_fetch_add(cnt, 1u, __ATOMIC_RELAXED, __HIP_MEMORY_SCOPE_AGENT);
    if (a == 29u) {
      unsigned* root = bar + 8 * 16;
      unsigned r = __hip_atomic_fetch_add(root, 1u, __ATOMIC_RELAXED, __HIP_MEMORY_SCOPE_AGENT);
      if (r == 7u) {
        __hip_atomic_store(root, 0u, __ATOMIC_RELAXED, __HIP_MEMORY_SCOPE_AGENT);
#pragma unroll
        for (int i = 0; i < 8; ++i)
          __hip_atomic_store(bar + i * 16, 0u, __ATOMIC_RELAXED, __HIP_MEMORY_SCOPE_AGENT);
        asm volatile("s_waitcnt vmcnt(0)" ::: "memory");
#pragma unroll
        for (int i = 0; i < 8; ++i)
          __hip_atomic_store(bar + (9 + i) * 16, target, __ATOMIC_RELAXED, __HIP_MEMORY_SCOPE_AGENT);
      }
    }
    while (__hip_atomic_load(gen, __ATOMIC_RELAXED, __HIP_MEMORY_SCOPE_AGENT) < target)
      __builtin_amdgcn_s_sleep(1);
  }
  __syncthreads();
}

// ---------------- precompute: xwxb[v][c] = sum_k embed[v][k]*Wx[k][c] + b[c]
__global__ __launch_bounds__(256) void precompute_k(const float* __restrict__ embed,
                                                    const float* __restrict__ Wx,
                                                    const float* __restrict__ bias,
                                                    float* __restrict__ xwxb) {
  __shared__ float embT[HH * 17];
  const int tid = threadIdx.x;
  const int v0 = blockIdx.y * 16;
  const int c0 = blockIdx.x * 256 + (tid & 63) * 4;
  const int vg = tid >> 6;
  for (int i = tid; i < 16 * 160; i += 256) {
    int vr = i / 160, kq = i - vr * 160;
    int v = v0 + vr; if (v >= VV) v = VV - 1;
    float4 e = *(const float4*)&embed[(size_t)v * HH + kq * 4];
    embT[(kq * 4 + 0) * 17 + vr] = e.x;
    embT[(kq * 4 + 1) * 17 + vr] = e.y;
    embT[(kq * 4 + 2) * 17 + vr] = e.z;
    embT[(kq * 4 + 3) * 17 + vr] = e.w;
  }
  __syncthreads();
  float acc[16];
#pragma unroll
  for (int i = 0; i < 16; ++i) acc[i] = 0.f;
#pragma unroll 4
  for (int k = 0; k < HH; ++k) {
    float4 wv = *(const float4*)&Wx[(size_t)k * H4 + c0];
#pragma unroll
    for (int i = 0; i < 4; ++i) {
      float e = embT[k * 17 + vg * 4 + i];
      acc[i * 4 + 0] += e * wv.x;
      acc[i * 4 + 1] += e * wv.y;
      acc[i * 4 + 2] += e * wv.z;
      acc[i * 4 + 3] += e * wv.w;
    }
  }
  float4 bv = *(const float4*)&bias[c0];
#pragma unroll
  for (int i = 0; i < 4; ++i) {
    int v = v0 + vg * 4 + i;
    if (v < VV) {
      float4 r;
      r.x = acc[i * 4 + 0] + bv.x; r.y = acc[i * 4 + 1] + bv.y;
      r.z = acc[i * 4 + 2] + bv.z; r.w = acc[i * 4 + 3] + bv.w;
      *(float4*)&xwxb[(size_t)v * H4 + c0] = r;
    }
  }
}

// ---------------- init: barrier zero + initial LSTM step (h0=c0=0, tok=0) + joint t=0
__global__ __launch_bounds__(256) void init_k(const float* __restrict__ tn,
                                              const float* __restrict__ embed,
                                              const float* __restrict__ Wx,
                                              const float* __restrict__ bias,
                                              float* ws, int use_table) {
  const int tid = threadIdx.x, bid = blockIdx.x;
  const int b = tid & 31, c8 = tid >> 5;
  const int j = bid * 8 + c8;
  if (bid == 0) {
    unsigned* bar = (unsigned*)(ws + O_BAR);
    for (int i = tid; i < 17 * 16; i += 256) bar[i] = 0u;
  }
  const float* xwxb = ws + O_XWXB;
  float g4[4];
  if (use_table) {
#pragma unroll
    for (int g = 0; g < 4; ++g) g4[g] = xwxb[g * HH + j];  // token 0 row
  } else {
#pragma unroll
    for (int g = 0; g < 4; ++g) g4[g] = bias[g * HH + j];
#pragma unroll 4
    for (int k = 0; k < HH; ++k) {
      float xv = embed[k];  // token 0 row
#pragma unroll
      for (int g = 0; g < 4; ++g) g4[g] += xv * Wx[(size_t)k * H4 + g * HH + j];
    }
  }
  float c1 = sigf(g4[0]) * tanhf(g4[2]);
  float h1 = sigf(g4[3]) * tanhf(c1);
  ws[O_CT + j * 32 + b] = c1;
  ws[O_HT + j * 32 + b] = h1;
  ws[O_PNT + j * 32 + b] = h1;
  ws[O_JOINT + j * 32 + b] = tanhf(tn[(size_t)b * TT * HH + j] + h1);
}

// ---------------- persistent decode kernel
__global__ __launch_bounds__(512) void decode_k(const float* __restrict__ tn,
                                                const float* __restrict__ embed,
                                                const float* __restrict__ Wx,
                                                const float* __restrict__ bias,
                                                const float* __restrict__ Wh,
                                                const float* __restrict__ Wc,
                                                const float* __restrict__ bc,
                                                float* __restrict__ out,
                                                float* ws, int use_table) {
  // bufA: logits -> full 640x32 jointT tile (restaged per step)
  //       gate   -> Wh slice [640][32 lc] staged ONCE (lc: 8 units x 4 gates)
  // bufB: logits -> part[8][1152] + lm/lsv/lix (9216+1584=10800)
  //       gate   -> per-half hT staging (10240) overlaid by part, then B scratch
  __shared__ float bufA[20480];
  __shared__ float bufB[11008];
  __shared__ float hwh_s[1056];   // gate: hwh[lc(32) stride 33][b]  (persists A->B)
  __shared__ float c_s[256];      // gate: c state (LDS-resident)
  __shared__ float pn_s[256];     // gate: out_PN state
  __shared__ int s_tok[32];
  __shared__ int s_upd[32];
  __shared__ int s_ptok[32];
  __shared__ float s_scores[32];
  const int tid = threadIdx.x, bid = blockIdx.x;
  unsigned* bar = (unsigned*)(ws + O_BAR);
  const float* xwxb = ws + O_XWXB;
  const bool is_log = (bid < NLOG);
  const bool is_gate = (bid >= NLOG) && (bid < NLOG + NGATE);
  const int q = bid - NLOG;  // gate slice index

  if (tid < 32) { s_ptok[tid] = 0; s_scores[tid] = 0.f; }
  if (is_gate) {
    // one-time: stage this block's Wh slice into LDS (strided read, cost paid once)
    for (int i = tid; i < 20480; i += 512) {
      int k = i >> 5, lc = i & 31;
      bufA[i] = Wh[(size_t)k * H4 + (lc >> 3) * HH + q * 8 + (lc & 7)];
    }
    if (tid < 256) {
      const int jj = tid >> 5, b = tid & 31;
      c_s[jj * 32 + b] = ws[O_CT + (q * 8 + jj) * 32 + b];
      pn_s[jj * 32 + b] = ws[O_PNT + (q * 8 + jj) * 32 + b];
    }
  }
  __syncthreads();

  // ---- GEMM thread decomposition: 8 cols x 4 batches per thread, 16-way K split
  const int lane = tid & 63, wvv = tid >> 6;
  const int sub = lane >> 5;          // K-split parity
  const int cg  = lane & 3;           // 4 col-groups of 8 cols
  const int bg  = (lane >> 2) & 7;    // 8 batch-groups of 4
  const int kb  = (wvv * 2 + sub) * 40;   // logits: 40-row K chunk of 640
  const int kbh = (wvv * 2 + sub) * 20;   // gate: 20-row K chunk of each 320-half
  const float* wbase_log = nullptr;
  if (is_log) {
    int c = bid * 32 + cg * 8;
    if (c > VV - 8) c = VV - 8;   // clamp (dup cols; masked at logits stage)
    wbase_log = Wc + (size_t)kb * VV + c;
  }

  unsigned epoch = 0;
  for (int t = 0; t < TT; ++t) {
    float tnv = 0.f;  // gate: tn[b][t+1][8q+jj], prefetched (held across barrier 1)

    // ================= phase A =================
    if (is_log || is_gate) {
      float acc[32];  // acc[c*4+b]: 8 cols x 4 batches
#pragma unroll
      for (int i = 0; i < 32; ++i) acc[i] = 0.f;

      if (is_log) {
        stage_sc1_full(bufA, ws + O_JOINT, tid);
        __syncthreads();
        const float* wp = wbase_log;
        const float* jp = bufA + kb * 32 + bg * 4;
#pragma unroll 4
        for (int kk = 0; kk < 40; ++kk) {
          float4 w0 = *(const float4*)(wp);
          float4 w1 = *(const float4*)(wp + 4);
          float4 jv = *(const float4*)(jp);
          wp += VV;
          jp += 32;
          acc[0]  += w0.x * jv.x; acc[1]  += w0.x * jv.y; acc[2]  += w0.x * jv.z; acc[3]  += w0.x * jv.w;
          acc[4]  += w0.y * jv.x; acc[5]  += w0.y * jv.y; acc[6]  += w0.y * jv.z; acc[7]  += w0.y * jv.w;
          acc[8]  += w0.z * jv.x; acc[9]  += w0.z * jv.y; acc[10] += w0.z * jv.z; acc[11] += w0.z * jv.w;
          acc[12] += w0.w * jv.x; acc[13] += w0.w * jv.y; acc[14] += w0.w * jv.z; acc[15] += w0.w * jv.w;
          acc[16] += w1.x * jv.x; acc[17] += w1.x * jv.y; acc[18] += w1.x * jv.z; acc[19] += w1.x * jv.w;
          acc[20] += w1.y * jv.x; acc[21] += w1.y * jv.y; acc[22] += w1.y * jv.z; acc[23] += w1.y * jv.w;
          acc[24] += w1.z * jv.x; acc[25] += w1.z * jv.y; acc[26] += w1.z * jv.z; acc[27] += w1.z * jv.w;
          acc[28] += w1.w * jv.x; acc[29] += w1.w * jv.y; acc[30] += w1.w * jv.z; acc[31] += w1.w * jv.w;
        }
      } else {
        if (tid < 256 && t + 1 < TT)
          tnv = tn[((size_t)(tid & 31) * TT + (t + 1)) * HH + q * 8 + (tid >> 5)];
        for (int half = 0; half < 2; ++half) {
          __syncthreads();  // previous bufB readers done (prev half FMA / B scratch)
          stage_sc1_half(bufB, ws + O_HT + half * 10240, tid);
          __syncthreads();
          const float* wp = bufA + ((half * 320 + kbh) * 32) + cg * 8;  // LDS weights
          const float* jp = bufB + kbh * 32 + bg * 4;
#pragma unroll 4
          for (int kk = 0; kk < 20; ++kk) {
            float4 w0 = *(const float4*)(wp);
            float4 w1 = *(const float4*)(wp + 4);
            float4 jv = *(const float4*)(jp);
            wp += 32;
            jp += 32;
            acc[0]  += w0.x * jv.x; acc[1]  += w0.x * jv.y; acc[2]  += w0.x * jv.z; acc[3]  += w0.x * jv.w;
            acc[4]  += w0.y * jv.x; acc[5]  += w0.y * jv.y; acc[6]  += w0.y * jv.z; acc[7]  += w0.y * jv.w;
            acc[8]  += w0.z * jv.x; acc[9]  += w0.z * jv.y; acc[10] += w0.z * jv.z; acc[11] += w0.z * jv.w;
            acc[12] += w0.w * jv.x; acc[13] += w0.w * jv.y; acc[14] += w0.w * jv.z; acc[15] += w0.w * jv.w;
            acc[16] += w1.x * jv.x; acc[17] += w1.x * jv.y; acc[18] += w1.x * jv.z; acc[19] += w1.x * jv.w;
            acc[20] += w1.y * jv.x; acc[21] += w1.y * jv.y; acc[22] += w1.y * jv.z; acc[23] += w1.y * jv.w;
            acc[24] += w1.z * jv.x; acc[25] += w1.z * jv.y; acc[26] += w1.z * jv.z; acc[27] += w1.z * jv.w;
            acc[28] += w1.w * jv.x; acc[29] += w1.w * jv.y; acc[30] += w1.w * jv.z; acc[31] += w1.w * jv.w;
          }
        }
        __syncthreads();  // all bufB staging reads done; bufB now reused as part
      }

#pragma unroll
      for (int i = 0; i < 32; ++i) acc[i] += __shfl_xor(acc[i], 32);
      float* part = bufB;  // [8 waves][32 cols * 36]
      if (sub == 0) {
        float* pb = part + wvv * 1152 + bg * 4;
#pragma unroll
        for (int c = 0; c < 8; ++c)
          *(float4*)&pb[(cg * 8 + c) * 36] =
              make_float4(acc[c * 4 + 0], acc[c * 4 + 1], acc[c * 4 + 2], acc[c * 4 + 3]);
      }
      __syncthreads();

      const int b = tid & 31, colg = tid >> 5;
      if (is_log) {
        float* lm = bufB + 9216;
        float* lsv = bufB + 9744;
        int* lix = (int*)(bufB + 10272);
        float m = -FLT_MAX; int ix = 0;
        float lv[2];
#pragma unroll
        for (int i = 0; i < 2; ++i) {
          const int cl = colg * 2 + i;
          float s = 0.f;
#pragma unroll
          for (int qq = 0; qq < 8; ++qq) s += part[qq * 1152 + cl * 36 + b];
          int cgl = bid * 32 + cl;
          float l = (cgl < VV) ? s + bc[cgl] : -FLT_MAX;
          lv[i] = l;
          if (l > m) { m = l; ix = cgl; }
        }
        float e = 0.f;
        if (m > -FLT_MAX) {
#pragma unroll
          for (int i = 0; i < 2; ++i) e += expf(lv[i] - m);
        }
        lm[colg * 33 + b] = m; lsv[colg * 33 + b] = e; lix[colg * 33 + b] = ix;
        __syncthreads();
        if (tid < 32) {
          float m2 = lm[tid], s2 = lsv[tid]; int ix2 = lix[tid];
#pragma unroll
          for (int qq = 1; qq < 16; ++qq) {
            float M = lm[qq * 33 + tid], S = lsv[qq * 33 + tid]; int I = lix[qq * 33 + tid];
            if (M > m2) { s2 = s2 * expf(m2 - M) + S; m2 = M; ix2 = I; }
            else if (M > -FLT_MAX) { s2 += S * expf(M - m2); }
          }
          stc1(&ws[O_PM + bid * 32 + tid], m2);
          stc1(&ws[O_PS + bid * 32 + tid], s2);
          stc1(&ws[O_PI + bid * 32 + tid], __int_as_float(ix2));
        }
      } else {
#pragma unroll
        for (int i = 0; i < 2; ++i) {
          const int cl = colg * 2 + i;
          float s = 0.f;
#pragma unroll
          for (int qq = 0; qq < 8; ++qq) s += part[qq * 1152 + cl * 36 + b];
          hwh_s[cl * 33 + b] = s;  // stays in LDS — no global round-trip
        }
      }
    }
    epoch++;
    grid_bar(bar, epoch);  // gate blocks read partials next (sc1 loads; no acquire)

    // ================= phase B (gate blocks only) =================
    if (is_gate) {
      float* rm = bufB;               // [16*33]
      float* rs = bufB + 528;
      int* ri = (int*)(bufB + 1056);
      float* gmat = bufB + 1584;      // [32*33]
      float* xl = bufB + 2640;        // [32*161] fallback staging
      const int r = tid & 31, c16 = tid >> 5;
      {
        float m = -FLT_MAX, s = 0.f; int ix = 0;
#pragma unroll
        for (int i = 0; i < 10; ++i) {
          int idx = c16 * 10 + i;
          bool v = (idx < NLOG);
          int ic = v ? idx : 0;
          float M = ldc1(&ws[O_PM + ic * 32 + r]);
          float S = ldc1(&ws[O_PS + ic * 32 + r]);
          int I = __float_as_int(ldc1(&ws[O_PI + ic * 32 + r]));
          if (!v) { M = -FLT_MAX; S = 0.f; I = 0; }
          if (M > m) { s = s * expf(m - M) + S; m = M; ix = I; }
          else if (M > -FLT_MAX) { s += S * expf(M - m); }
        }
        rm[c16 * 33 + r] = m; rs[c16 * 33 + r] = s; ri[c16 * 33 + r] = ix;
      }
      __syncthreads();
      if (tid < 32) {
        float m = rm[tid], s = rs[tid]; int ix = ri[tid];
#pragma unroll
        for (int qq = 1; qq < 16; ++qq) {
          float M = rm[qq * 33 + tid], S = rs[qq * 33 + tid]; int I = ri[qq * 33 + tid];
          if (M > m) { s = s * expf(m - M) + S; m = M; ix = I; }
          else { s += S * expf(M - m); }
        }
        int pos = ix;
        int upd = (pos != 0) ? 1 : 0;
        int ntk = upd ? pos : s_ptok[tid];
        s_tok[tid] = ntk; s_upd[tid] = upd; s_ptok[tid] = ntk;
        if (bid == NLOG) {  // emitter
          float sc = s_scores[tid];
          if (upd) sc -= logf(s);
          s_scores[tid] = sc;
          out[BB + (size_t)tid * TT + t] = upd ? (float)pos : 0.0f;
          if (t == TT - 1) out[tid] = sc;
        }
      }
      __syncthreads();

      // gate pre-activations for the block's 32 strided cols
      const int b = tid & 31;
      float gv[2];
#pragma unroll
      for (int h = 0; h < 2; ++h) {
        int lc = (tid >> 5) + h * 16;
        int wcol = (lc >> 3) * HH + q * 8 + (lc & 7);
        float v = hwh_s[lc * 33 + b];
        if (use_table) v += xwxb[(size_t)s_tok[b] * H4 + wcol];
        else v += bias[wcol];
        gv[h] = v;
      }
      if (!use_table) {
        for (int st = 0; st < 4; ++st) {
          const int k0 = st * 160;
          __syncthreads();
          for (int i = tid; i < 32 * 160; i += 512) {
            int bb = i / 160, kk = i - bb * 160;
            xl[bb * 161 + kk] = embed[(size_t)s_tok[bb] * HH + k0 + kk];
          }
          __syncthreads();
          for (int k = 0; k < 160; ++k) {
            float xv = xl[b * 161 + k];
#pragma unroll
            for (int h = 0; h < 2; ++h) {
              int lc = (tid >> 5) + h * 16;
              int wcol = (lc >> 3) * HH + q * 8 + (lc & 7);
              gv[h] += xv * Wx[(size_t)(k0 + k) * H4 + wcol];
            }
          }
        }
      }
#pragma unroll
      for (int h = 0; h < 2; ++h) {
        int lc = (tid >> 5) + h * 16;
        gmat[lc * 33 + b] = gv[h];
      }
      __syncthreads();
      if (tid < 256) {
        const int jj = tid >> 5, b2 = tid & 31;
        float gi = gmat[(0 * 8 + jj) * 33 + b2];
        float gf = gmat[(1 * 8 + jj) * 33 + b2];
        float gg = gmat[(2 * 8 + jj) * 33 + b2];
        float go = gmat[(3 * 8 + jj) * 33 + b2];
        float cold = c_s[jj * 32 + b2];
        float c2 = sigf(gf) * cold + sigf(gi) * tanhf(gg);
        float h2 = sigf(go) * tanhf(c2);
        float pv;
        if (s_upd[b2]) {
          c_s[jj * 32 + b2] = c2;
          pn_s[jj * 32 + b2] = h2;
          stc1(&ws[O_HT + (q * 8 + jj) * 32 + b2], h2);   // sc1 write-through
          pv = h2;
        } else {
          pv = pn_s[jj * 32 + b2];
        }
        if (t + 1 < TT)
          stc1(&ws[O_JOINT + (q * 8 + jj) * 32 + b2], tanhf(tnv + pv));  // sc1
      }
    }
    epoch++;
    grid_bar(bar, epoch);  // next A stages jointT / hT (sc1 bursts; no acquire)
  }
}

extern "C" void kernel_launch(void* const* d_in, const int* in_sizes, int n_in,
                              void* d_out, int out_size, void* d_ws, size_t ws_size,
                              hipStream_t stream) {
  const float* tn    = (const float*)d_in[0];
  const float* embed = (const float*)d_in[1];
  const float* Wx    = (const float*)d_in[2];
  const float* Wh    = (const float*)d_in[3];
  const float* bias  = (const float*)d_in[4];
  const float* Wc    = (const float*)d_in[5];
  const float* bc    = (const float*)d_in[6];
  float* out = (float*)d_out;
  float* ws  = (float*)d_ws;

  const size_t need_table = (size_t)(O_XWXB + XWXB_ELEMS) * sizeof(float);
  const int use_table = (ws_size >= need_table) ? 1 : 0;

  if (use_table)
    hipLaunchKernelGGL(precompute_k, dim3(10, 313), dim3(256), 0, stream,
                       embed, Wx, bias, ws + O_XWXB);
  hipLaunchKernelGGL(init_k, dim3(80), dim3(256), 0, stream, tn, embed, Wx, bias, ws, use_table);
  hipLaunchKernelGGL(decode_k, dim3(NB), dim3(512), 0, stream,
                     tn, embed, Wx, bias, Wh, Wc, bc, out, ws, use_table);
}

// Round 7
// 29038.687 us; speedup vs baseline: 1.1906x; 1.0453x over previous
//
#include <hip/hip_runtime.h>
#include <float.h>

// Batched transducer greedy decode, B=32 T=1000 H=640 V=5000, fp32.
// Persistent kernel, 240 blocks x 512 thr, 2 grid barriers/step.
// R7 (revised memory model from R0-R6 counters):
//  - sc0/sc1 asm loads bypass L2 by construction; PLAIN ws loads are cacheable
//    but the per-step Wc stream (~3.2MB lines/XCD) LRU-evicts anything else in
//    L2 (R4's WhP 6.7GB refetch). So weights must be LDS or come with the
//    Wc-like access pattern; cross-block data stays on the sc1/MALL path.
//  - R6 gate phase serialized (2 stage shots + 4 syncs) and lost to R4's
//    pipelined streaming. R7 gate A: weights LDS-resident (staged once), hT
//    read DIRECTLY from ws with depth-2 register-pipelined sc1 loads (16 in
//    flight) -> MALL latency hides under FMAs; zero per-step staging/syncs.
//  - Phase B partial gather: 30 sc1 loads HOISTED to registers (1 latency shot
//    instead of ~10 dependent MALL round-trips).
//  - Barrier: monotonic no-reset counters (epoch-valued), 128B-padded slots;
//    removes reset stores + mid-barrier vmcnt drain.
#define BB 32
#define TT 1000
#define HH 640
#define H4 2560
#define VV 5000
#define NLOG 157   // logits tiles, 32 cols each (last tile 8 valid)
#define NGATE 80   // gate blocks: 8 units x 4 gates each, weights in LDS
#define NB   240   // 8 barrier groups x 30

// workspace layout (float offsets)
#define O_JOINT 0        // jointT[j][b]  (640x32)   cross-block (sc1 path)
#define O_HT    20480    // hT[j][b]      (640x32)   cross-block (sc1 path)
#define O_PM    40960    // partial max    [157*32]  cross-block (sc1 path)
#define O_PS    46080    // partial sumexp [157*32]  cross-block (sc1 path)
#define O_PI    51200    // partial argmax [157*32] (int bits)    (sc1 path)
#define O_BAR   56320    // barrier: 17 slots x 32 u32 (128B padded)
#define O_CT    56960    // initial c (640x32) — consumed once at kernel start
#define O_PNT   77440    // initial out_PN (640x32) — consumed once
#define O_XWXB  97920    // embed@Wx + b  (5000x2560), optional
#define XWXB_ELEMS ((size_t)VV * (size_t)H4)

typedef unsigned int u32;
typedef unsigned long long u64;

__device__ __forceinline__ float sigf(float x) { return 1.0f / (1.0f + expf(-x)); }

// ---- sc1 (MALL-coherent, L2-bypassing) access helpers.
__device__ __forceinline__ float ldc1(const float* p) {
  u32 v = __hip_atomic_load((const u32*)p, __ATOMIC_RELAXED, __HIP_MEMORY_SCOPE_AGENT);
  return __uint_as_float(v);
}
__device__ __forceinline__ void stc1(float* p, float x) {
  __hip_atomic_store((u32*)p, __float_as_uint(x), __ATOMIC_RELAXED, __HIP_MEMORY_SCOPE_AGENT);
}
__device__ __forceinline__ float2 ldc2(const float* p) {
  u64 v = __hip_atomic_load((const u64*)p, __ATOMIC_RELAXED, __HIP_MEMORY_SCOPE_AGENT);
  union { u64 u; float2 f; } c; c.u = v;
  return c.f;
}

// issue 8 k-rows' worth of jv (16 x 8B sc1 loads, back-to-back, no use -> all
// in flight; backend inserts the waitcnt only at first FMA use of the buffer)
__device__ __forceinline__ void ldc8(float2* d, const float* src) {
#pragma unroll
  for (int i = 0; i < 8; ++i) {
    d[2 * i]     = ldc2(src + i * 32);
    d[2 * i + 1] = ldc2(src + i * 32 + 2);
  }
}

// 8 k-rows of FMA: weights from LDS (row stride 32), jv from register buffer
__device__ __forceinline__ void fma8(float* acc, const float* w, const float2* j) {
#pragma unroll
  for (int i = 0; i < 8; ++i) {
    float4 w0 = *(const float4*)(w + i * 32);
    float4 w1 = *(const float4*)(w + i * 32 + 4);
    float jx = j[2 * i].x, jy = j[2 * i].y;
    float jz = j[2 * i + 1].x, jw = j[2 * i + 1].y;
    acc[0]  += w0.x * jx; acc[1]  += w0.x * jy; acc[2]  += w0.x * jz; acc[3]  += w0.x * jw;
    acc[4]  += w0.y * jx; acc[5]  += w0.y * jy; acc[6]  += w0.y * jz; acc[7]  += w0.y * jw;
    acc[8]  += w0.z * jx; acc[9]  += w0.z * jy; acc[10] += w0.z * jz; acc[11] += w0.z * jw;
    acc[12] += w0.w * jx; acc[13] += w0.w * jy; acc[14] += w0.w * jz; acc[15] += w0.w * jw;
    acc[16] += w1.x * jx; acc[17] += w1.x * jy; acc[18] += w1.x * jz; acc[19] += w1.x * jw;
    acc[20] += w1.y * jx; acc[21] += w1.y * jy; acc[22] += w1.y * jz; acc[23] += w1.y * jw;
    acc[24] += w1.z * jx; acc[25] += w1.z * jy; acc[26] += w1.z * jz; acc[27] += w1.z * jw;
    acc[28] += w1.w * jx; acc[29] += w1.w * jy; acc[30] += w1.w * jz; acc[31] += w1.w * jw;
  }
}

// ---- sc1 burst: 20480 floats global -> LDS, 10 dwordx4/thread, one vmcnt.
__device__ __forceinline__ void stage_sc1_full(float* dst, const float* src, int tid) {
  const float* p0 = src + 4 * (tid + 0 * 512);
  const float* p1 = src + 4 * (tid + 1 * 512);
  const float* p2 = src + 4 * (tid + 2 * 512);
  const float* p3 = src + 4 * (tid + 3 * 512);
  const float* p4 = src + 4 * (tid + 4 * 512);
  const float* p5 = src + 4 * (tid + 5 * 512);
  const float* p6 = src + 4 * (tid + 6 * 512);
  const float* p7 = src + 4 * (tid + 7 * 512);
  const float* p8 = src + 4 * (tid + 8 * 512);
  const float* p9 = src + 4 * (tid + 9 * 512);
  float4 a0, a1, a2, a3, a4, a5, a6, a7, a8, a9;
  asm volatile(
      "global_load_dwordx4 %0, %10, off sc0 sc1\n\t"
      "global_load_dwordx4 %1, %11, off sc0 sc1\n\t"
      "global_load_dwordx4 %2, %12, off sc0 sc1\n\t"
      "global_load_dwordx4 %3, %13, off sc0 sc1\n\t"
      "global_load_dwordx4 %4, %14, off sc0 sc1\n\t"
      "global_load_dwordx4 %5, %15, off sc0 sc1\n\t"
      "global_load_dwordx4 %6, %16, off sc0 sc1\n\t"
      "global_load_dwordx4 %7, %17, off sc0 sc1\n\t"
      "global_load_dwordx4 %8, %18, off sc0 sc1\n\t"
      "global_load_dwordx4 %9, %19, off sc0 sc1\n\t"
      "s_waitcnt vmcnt(0)"
      : "=&v"(a0), "=&v"(a1), "=&v"(a2), "=&v"(a3), "=&v"(a4),
        "=&v"(a5), "=&v"(a6), "=&v"(a7), "=&v"(a8), "=&v"(a9)
      : "v"(p0), "v"(p1), "v"(p2), "v"(p3), "v"(p4),
        "v"(p5), "v"(p6), "v"(p7), "v"(p8), "v"(p9)
      : "memory");
  float4* d4 = (float4*)dst;
  d4[tid + 0 * 512] = a0;
  d4[tid + 1 * 512] = a1;
  d4[tid + 2 * 512] = a2;
  d4[tid + 3 * 512] = a3;
  d4[tid + 4 * 512] = a4;
  d4[tid + 5 * 512] = a5;
  d4[tid + 6 * 512] = a6;
  d4[tid + 7 * 512] = a7;
  d4[tid + 8 * 512] = a8;
  d4[tid + 9 * 512] = a9;
}

// grid barrier: fence-free, monotonic no-reset counters (epoch-valued).
// cnt[g] at 128B stride; a == 30*epoch-1 detects the group's last arrival;
// root counts 8 leaders/epoch (strictly epoch-ordered: a leader for epoch e
// can only fire after gen>=e-1, which requires all epoch e-1 root adds).
__device__ __forceinline__ void grid_bar(unsigned* bar, unsigned epoch) {
  __syncthreads();
  if (threadIdx.x == 0) {
    const int g = (int)blockIdx.x / 30;
    unsigned* cnt = bar + g * 32;
    unsigned* gen = bar + (9 + g) * 32;
    asm volatile("s_waitcnt vmcnt(0)" ::: "memory");
    unsigned a = __hip_atomic_fetch_add(cnt, 1u, __ATOMIC_RELAXED, __HIP_MEMORY_SCOPE_AGENT);
    if (a == 30u * epoch - 1u) {
      unsigned* root = bar + 8 * 32;
      unsigned r = __hip_atomic_fetch_add(root, 1u, __ATOMIC_RELAXED, __HIP_MEMORY_SCOPE_AGENT);
      if (r == 8u * epoch - 1u) {
#pragma unroll
        for (int i = 0; i < 8; ++i)
          __hip_atomic_store(bar + (9 + i) * 32, epoch, __ATOMIC_RELAXED, __HIP_MEMORY_SCOPE_AGENT);
      }
    }
    while (__hip_atomic_load(gen, __ATOMIC_RELAXED, __HIP_MEMORY_SCOPE_AGENT) < epoch)
      __builtin_amdgcn_s_sleep(1);
  }
  __syncthreads();
}

// ---------------- precompute: xwxb[v][c] = sum_k embed[v][k]*Wx[k][c] + b[c]
__global__ __launch_bounds__(256) void precompute_k(const float* __restrict__ embed,
                                                    const float* __restrict__ Wx,
                                                    const float* __restrict__ bias,
                                                    float* __restrict__ xwxb) {
  __shared__ float embT[HH * 17];
  const int tid = threadIdx.x;
  const int v0 = blockIdx.y * 16;
  const int c0 = blockIdx.x * 256 + (tid & 63) * 4;
  const int vg = tid >> 6;
  for (int i = tid; i < 16 * 160; i += 256) {
    int vr = i / 160, kq = i - vr * 160;
    int v = v0 + vr; if (v >= VV) v = VV - 1;
    float4 e = *(const float4*)&embed[(size_t)v * HH + kq * 4];
    embT[(kq * 4 + 0) * 17 + vr] = e.x;
    embT[(kq * 4 + 1) * 17 + vr] = e.y;
    embT[(kq * 4 + 2) * 17 + vr] = e.z;
    embT[(kq * 4 + 3) * 17 + vr] = e.w;
  }
  __syncthreads();
  float acc[16];
#pragma unroll
  for (int i = 0; i < 16; ++i) acc[i] = 0.f;
#pragma unroll 4
  for (int k = 0; k < HH; ++k) {
    float4 wv = *(const float4*)&Wx[(size_t)k * H4 + c0];
#pragma unroll
    for (int i = 0; i < 4; ++i) {
      float e = embT[k * 17 + vg * 4 + i];
      acc[i * 4 + 0] += e * wv.x;
      acc[i * 4 + 1] += e * wv.y;
      acc[i * 4 + 2] += e * wv.z;
      acc[i * 4 + 3] += e * wv.w;
    }
  }
  float4 bv = *(const float4*)&bias[c0];
#pragma unroll
  for (int i = 0; i < 4; ++i) {
    int v = v0 + vg * 4 + i;
    if (v < VV) {
      float4 r;
      r.x = acc[i * 4 + 0] + bv.x; r.y = acc[i * 4 + 1] + bv.y;
      r.z = acc[i * 4 + 2] + bv.z; r.w = acc[i * 4 + 3] + bv.w;
      *(float4*)&xwxb[(size_t)v * H4 + c0] = r;
    }
  }
}

// ---------------- init: barrier zero + initial LSTM step (h0=c0=0, tok=0) + joint t=0
__global__ __launch_bounds__(256) void init_k(const float* __restrict__ tn,
                                              const float* __restrict__ embed,
                                              const float* __restrict__ Wx,
                                              const float* __restrict__ bias,
                                              float* ws, int use_table) {
  const int tid = threadIdx.x, bid = blockIdx.x;
  const int b = tid & 31, c8 = tid >> 5;
  const int j = bid * 8 + c8;
  if (bid == 0) {
    unsigned* bar = (unsigned*)(ws + O_BAR);
    for (int i = tid; i < 17 * 32; i += 256) bar[i] = 0u;
  }
  const float* xwxb = ws + O_XWXB;
  float g4[4];
  if (use_table) {
#pragma unroll
    for (int g = 0; g < 4; ++g) g4[g] = xwxb[g * HH + j];  // token 0 row
  } else {
#pragma unroll
    for (int g = 0; g < 4; ++g) g4[g] = bias[g * HH + j];
#pragma unroll 4
    for (int k = 0; k < HH; ++k) {
      float xv = embed[k];  // token 0 row
#pragma unroll
      for (int g = 0; g < 4; ++g) g4[g] += xv * Wx[(size_t)k * H4 + g * HH + j];
    }
  }
  float c1 = sigf(g4[0]) * tanhf(g4[2]);
  float h1 = sigf(g4[3]) * tanhf(c1);
  ws[O_CT + j * 32 + b] = c1;
  ws[O_HT + j * 32 + b] = h1;
  ws[O_PNT + j * 32 + b] = h1;
  ws[O_JOINT + j * 32 + b] = tanhf(tn[(size_t)b * TT * HH + j] + h1);
}

// ---------------- persistent decode kernel
__global__ __launch_bounds__(512) void decode_k(const float* __restrict__ tn,
                                                const float* __restrict__ embed,
                                                const float* __restrict__ Wx,
                                                const float* __restrict__ bias,
                                                const float* __restrict__ Wh,
                                                const float* __restrict__ Wc,
                                                const float* __restrict__ bc,
                                                float* __restrict__ out,
                                                float* ws, int use_table) {
  // bufA: logits -> full 640x32 jointT tile (restaged per step)
  //       gate   -> Wh slice [640][32 lc] staged ONCE (lc: 8 units x 4 gates)
  __shared__ float bufA[20480];
  __shared__ float bufB[11008];   // part[8][1152]+lm/lsv/lix; B: rm/rs/ri+gmat+xl
  __shared__ float hwh_s[1056];   // gate: hwh[lc(32) stride 33][b]  (persists A->B)
  __shared__ float c_s[256];      // gate: c state (LDS-resident)
  __shared__ float pn_s[256];     // gate: out_PN state
  __shared__ int s_tok[32];
  __shared__ int s_upd[32];
  __shared__ int s_ptok[32];
  __shared__ float s_scores[32];
  const int tid = threadIdx.x, bid = blockIdx.x;
  unsigned* bar = (unsigned*)(ws + O_BAR);
  const float* xwxb = ws + O_XWXB;
  const bool is_log = (bid < NLOG);
  const bool is_gate = (bid >= NLOG) && (bid < NLOG + NGATE);
  const int q = bid - NLOG;  // gate slice index

  if (tid < 32) { s_ptok[tid] = 0; s_scores[tid] = 0.f; }
  if (is_gate) {
    // one-time: stage this block's Wh slice into LDS (strided read, paid once)
    for (int i = tid; i < 20480; i += 512) {
      int k = i >> 5, lc = i & 31;
      bufA[i] = Wh[(size_t)k * H4 + (lc >> 3) * HH + q * 8 + (lc & 7)];
    }
    if (tid < 256) {
      const int jj = tid >> 5, b = tid & 31;
      c_s[jj * 32 + b] = ws[O_CT + (q * 8 + jj) * 32 + b];
      pn_s[jj * 32 + b] = ws[O_PNT + (q * 8 + jj) * 32 + b];
    }
  }
  __syncthreads();

  // ---- GEMM thread decomposition: 8 cols x 4 batches per thread, 16-way K split
  const int lane = tid & 63, wvv = tid >> 6;
  const int sub = lane >> 5;          // K-split parity
  const int cg  = lane & 3;           // 4 col-groups of 8 cols
  const int bg  = (lane >> 2) & 7;    // 8 batch-groups of 4
  const int kb  = (wvv * 2 + sub) * 40;   // this thread's 40-row K chunk
  const float* wbase_log = nullptr;
  if (is_log) {
    int c = bid * 32 + cg * 8;
    if (c > VV - 8) c = VV - 8;   // clamp (dup cols; masked at logits stage)
    wbase_log = Wc + (size_t)kb * VV + c;
  }

  unsigned epoch = 0;
  for (int t = 0; t < TT; ++t) {
    float tnv = 0.f;  // gate: tn[b][t+1][8q+jj], prefetched (held across barrier 1)

    // ================= phase A =================
    if (is_log || is_gate) {
      float acc[32];  // acc[c*4+b]: 8 cols x 4 batches
#pragma unroll
      for (int i = 0; i < 32; ++i) acc[i] = 0.f;

      if (is_log) {
        stage_sc1_full(bufA, ws + O_JOINT, tid);
        __syncthreads();
        const float* wp = wbase_log;
        const float* jp = bufA + kb * 32 + bg * 4;
#pragma unroll 4
        for (int kk = 0; kk < 40; ++kk) {
          float4 w0 = *(const float4*)(wp);
          float4 w1 = *(const float4*)(wp + 4);
          float4 jv = *(const float4*)(jp);
          wp += VV;
          jp += 32;
          acc[0]  += w0.x * jv.x; acc[1]  += w0.x * jv.y; acc[2]  += w0.x * jv.z; acc[3]  += w0.x * jv.w;
          acc[4]  += w0.y * jv.x; acc[5]  += w0.y * jv.y; acc[6]  += w0.y * jv.z; acc[7]  += w0.y * jv.w;
          acc[8]  += w0.z * jv.x; acc[9]  += w0.z * jv.y; acc[10] += w0.z * jv.z; acc[11] += w0.z * jv.w;
          acc[12] += w0.w * jv.x; acc[13] += w0.w * jv.y; acc[14] += w0.w * jv.z; acc[15] += w0.w * jv.w;
          acc[16] += w1.x * jv.x; acc[17] += w1.x * jv.y; acc[18] += w1.x * jv.z; acc[19] += w1.x * jv.w;
          acc[20] += w1.y * jv.x; acc[21] += w1.y * jv.y; acc[22] += w1.y * jv.z; acc[23] += w1.y * jv.w;
          acc[24] += w1.z * jv.x; acc[25] += w1.z * jv.y; acc[26] += w1.z * jv.z; acc[27] += w1.z * jv.w;
          acc[28] += w1.w * jv.x; acc[29] += w1.w * jv.y; acc[30] += w1.w * jv.z; acc[31] += w1.w * jv.w;
        }
      } else {
        if (tid < 256 && t + 1 < TT)
          tnv = tn[((size_t)(tid & 31) * TT + (t + 1)) * HH + q * 8 + (tid >> 5)];
        // depth-2 register-pipelined GEMM: weights LDS, hT direct sc1 from ws
        const float* hp = ws + O_HT + kb * 32 + bg * 4;
        const float* wp = bufA + kb * 32 + cg * 8;
        float2 bx[16], by[16];
        ldc8(bx, hp);              // k 0..7   (16 loads in flight)
        ldc8(by, hp + 256);        // k 8..15  (32 in flight)
        fma8(acc, wp, bx);         // k 0..7
        ldc8(bx, hp + 512);        // k 16..23
        fma8(acc, wp + 256, by);   // k 8..15
        ldc8(by, hp + 768);        // k 24..31
        fma8(acc, wp + 512, bx);   // k 16..23
        ldc8(bx, hp + 1024);       // k 32..39
        fma8(acc, wp + 768, by);   // k 24..31
        fma8(acc, wp + 1024, bx);  // k 32..39
      }

#pragma unroll
      for (int i = 0; i < 32; ++i) acc[i] += __shfl_xor(acc[i], 32);
      float* part = bufB;  // [8 waves][32 cols * 36]
      if (sub == 0) {
        float* pb = part + wvv * 1152 + bg * 4;
#pragma unroll
        for (int c = 0; c < 8; ++c)
          *(float4*)&pb[(cg * 8 + c) * 36] =
              make_float4(acc[c * 4 + 0], acc[c * 4 + 1], acc[c * 4 + 2], acc[c * 4 + 3]);
      }
      __syncthreads();

      const int b = tid & 31, colg = tid >> 5;
      if (is_log) {
        float* lm = bufB + 9216;
        float* lsv = bufB + 9744;
        int* lix = (int*)(bufB + 10272);
        float m = -FLT_MAX; int ix = 0;
        float lv[2];
#pragma unroll
        for (int i = 0; i < 2; ++i) {
          const int cl = colg * 2 + i;
          float s = 0.f;
#pragma unroll
          for (int qq = 0; qq < 8; ++qq) s += part[qq * 1152 + cl * 36 + b];
          int cgl = bid * 32 + cl;
          float l = (cgl < VV) ? s + bc[cgl] : -FLT_MAX;
          lv[i] = l;
          if (l > m) { m = l; ix = cgl; }
        }
        float e = 0.f;
        if (m > -FLT_MAX) {
#pragma unroll
          for (int i = 0; i < 2; ++i) e += expf(lv[i] - m);
        }
        lm[colg * 33 + b] = m; lsv[colg * 33 + b] = e; lix[colg * 33 + b] = ix;
        __syncthreads();
        if (tid < 32) {
          float m2 = lm[tid], s2 = lsv[tid]; int ix2 = lix[tid];
#pragma unroll
          for (int qq = 1; qq < 16; ++qq) {
            float M = lm[qq * 33 + tid], S = lsv[qq * 33 + tid]; int I = lix[qq * 33 + tid];
            if (M > m2) { s2 = s2 * expf(m2 - M) + S; m2 = M; ix2 = I; }
            else if (M > -FLT_MAX) { s2 += S * expf(M - m2); }
          }
          stc1(&ws[O_PM + bid * 32 + tid], m2);
          stc1(&ws[O_PS + bid * 32 + tid], s2);
          stc1(&ws[O_PI + bid * 32 + tid], __int_as_float(ix2));
        }
      } else {
#pragma unroll
        for (int i = 0; i < 2; ++i) {
          const int cl = colg * 2 + i;
          float s = 0.f;
#pragma unroll
          for (int qq = 0; qq < 8; ++qq) s += part[qq * 1152 + cl * 36 + b];
          hwh_s[cl * 33 + b] = s;  // stays in LDS — no global round-trip
        }
      }
    }
    epoch++;
    grid_bar(bar, epoch);  // gate blocks read partials next

    // ================= phase B (gate blocks only) =================
    if (is_gate) {
      float* rm = bufB;               // [16*33]
      float* rs = bufB + 528;
      int* ri = (int*)(bufB + 1056);
      float* gmat = bufB + 1584;      // [32*33]
      float* xl = bufB + 2640;        // [32*161] fallback staging
      const int r = tid & 31, c16 = tid >> 5;
      {
        // hoisted gather: all 30 sc1 loads issued before the combine (1 shot)
        float Ms[10], Ss[10]; int Is[10];
#pragma unroll
        for (int i = 0; i < 10; ++i) {
          int idx = c16 * 10 + i;
          bool v = (idx < NLOG);
          int ic = v ? idx : 0;
          Ms[i] = ldc1(&ws[O_PM + ic * 32 + r]);
          Ss[i] = ldc1(&ws[O_PS + ic * 32 + r]);
          Is[i] = __float_as_int(ldc1(&ws[O_PI + ic * 32 + r]));
          if (!v) { Ms[i] = -FLT_MAX; Ss[i] = 0.f; Is[i] = 0; }
        }
        float m = -FLT_MAX, s = 0.f; int ix = 0;
#pragma unroll
        for (int i = 0; i < 10; ++i) {
          if (Ms[i] > m) { s = s * expf(m - Ms[i]) + Ss[i]; m = Ms[i]; ix = Is[i]; }
          else if (Ms[i] > -FLT_MAX) { s += Ss[i] * expf(Ms[i] - m); }
        }
        rm[c16 * 33 + r] = m; rs[c16 * 33 + r] = s; ri[c16 * 33 + r] = ix;
      }
      __syncthreads();
      if (tid < 32) {
        float m = rm[tid], s = rs[tid]; int ix = ri[tid];
#pragma unroll
        for (int qq = 1; qq < 16; ++qq) {
          float M = rm[qq * 33 + tid], S = rs[qq * 33 + tid]; int I = ri[qq * 33 + tid];
          if (M > m) { s = s * expf(m - M) + S; m = M; ix = I; }
          else { s += S * expf(M - m); }
        }
        int pos = ix;
        int upd = (pos != 0) ? 1 : 0;
        int ntk = upd ? pos : s_ptok[tid];
        s_tok[tid] = ntk; s_upd[tid] = upd; s_ptok[tid] = ntk;
        if (bid == NLOG) {  // emitter
          float sc = s_scores[tid];
          if (upd) sc -= logf(s);
          s_scores[tid] = sc;
          out[BB + (size_t)tid * TT + t] = upd ? (float)pos : 0.0f;
          if (t == TT - 1) out[tid] = sc;
        }
      }
      __syncthreads();

      // gate pre-activations for the block's 32 strided cols
      const int b = tid & 31;
      float gv[2];
#pragma unroll
      for (int h = 0; h < 2; ++h) {
        int lc = (tid >> 5) + h * 16;
        int wcol = (lc >> 3) * HH + q * 8 + (lc & 7);
        float v = hwh_s[lc * 33 + b];
        if (use_table) v += xwxb[(size_t)s_tok[b] * H4 + wcol];
        else v += bias[wcol];
        gv[h] = v;
      }
      if (!use_table) {
        for (int st = 0; st < 4; ++st) {
          const int k0 = st * 160;
          __syncthreads();
          for (int i = tid; i < 32 * 160; i += 512) {
            int bb = i / 160, kk = i - bb * 160;
            xl[bb * 161 + kk] = embed[(size_t)s_tok[bb] * HH + k0 + kk];
          }
          __syncthreads();
          for (int k = 0; k < 160; ++k) {
            float xv = xl[b * 161 + k];
#pragma unroll
            for (int h = 0; h < 2; ++h) {
              int lc = (tid >> 5) + h * 16;
              int wcol = (lc >> 3) * HH + q * 8 + (lc & 7);
              gv[h] += xv * Wx[(size_t)(k0 + k) * H4 + wcol];
            }
          }
        }
      }
#pragma unroll
      for (int h = 0; h < 2; ++h) {
        int lc = (tid >> 5) + h * 16;
        gmat[lc * 33 + b] = gv[h];
      }
      __syncthreads();
      if (tid < 256) {
        const int jj = tid >> 5, b2 = tid & 31;
        float gi = gmat[(0 * 8 + jj) * 33 + b2];
        float gf = gmat[(1 * 8 + jj) * 33 + b2];
        float gg = gmat[(2 * 8 + jj) * 33 + b2];
        float go = gmat[(3 * 8 + jj) * 33 + b2];
        float cold = c_s[jj * 32 + b2];
        float c2 = sigf(gf) * cold + sigf(gi) * tanhf(gg);
        float h2 = sigf(go) * tanhf(c2);
        float pv;
        if (s_upd[b2]) {
          c_s[jj * 32 + b2] = c2;
          pn_s[jj * 32 + b2] = h2;
          stc1(&ws[O_HT + (q * 8 + jj) * 32 + b2], h2);   // sc1 write-through
          pv = h2;
        } else {
          pv = pn_s[jj * 32 + b2];
        }
        if (t + 1 < TT)
          stc1(&ws[O_JOINT + (q * 8 + jj) * 32 + b2], tanhf(tnv + pv));  // sc1
      }
    }
    epoch++;
    grid_bar(bar, epoch);  // next A reads jointT / hT
  }
}

extern "C" void kernel_launch(void* const* d_in, const int* in_sizes, int n_in,
                              void* d_out, int out_size, void* d_ws, size_t ws_size,
                              hipStream_t stream) {
  const float* tn    = (const float*)d_in[0];
  const float* embed = (const float*)d_in[1];
  const float* Wx    = (const float*)d_in[2];
  const float* Wh    = (const float*)d_in[3];
  const float* bias  = (const float*)d_in[4];
  const float* Wc    = (const float*)d_in[5];
  const float* bc    = (const float*)d_in[6];
  float* out = (float*)d_out;
  float* ws  = (float*)d_ws;

  const size_t need_table = (size_t)(O_XWXB + XWXB_ELEMS) * sizeof(float);
  const int use_table = (ws_size >= need_table) ? 1 : 0;

  if (use_table)
    hipLaunchKernelGGL(precompute_k, dim3(10, 313), dim3(256), 0, stream,
                       embed, Wx, bias, ws + O_XWXB);
  hipLaunchKernelGGL(init_k, dim3(80), dim3(256), 0, stream, tn, embed, Wx, bias, ws, use_table);
  hipLaunchKernelGGL(decode_k, dim3(NB), dim3(512), 0, stream,
                     tn, embed, Wx, bias, Wh, Wc, bc, out, ws, use_table);
}

// Round 9
// 19060.324 us; speedup vs baseline: 1.8140x; 1.5235x over previous
//
#include <hip/hip_runtime.h>
#include <float.h>

// Batched transducer greedy decode, B=32 T=1000 H=640 V=5000, fp32.
// Persistent kernel, 240 blocks x 512 thr, 2 grid barriers/step.
// R9 = R8 with the compile fix (__builtin_nontemporal_load requires a native
// clang vector type, not HIP_vector_type). Content identical to R8's plan:
// R4 topology (best measured: 23.7ms) + three orthogonal fixes:
//  1) Phase-B partial combine: all 30 sc1 loads HOISTED before the combine
//     (R4 had ~10 dependent MALL round-trips inside the loop).
//  2) Barrier: monotonic no-reset counters (epoch-valued), 128B-padded slots;
//     removes reset stores + mid-barrier vmcnt drain.
//  3) Streaming reads (WhP weight stream, xwxb token rows) use
//     __builtin_nontemporal_load -> no L2 pollution of Wc/tn resident lines.
#define BB 32
#define TT 1000
#define HH 640
#define H4 2560
#define VV 5000
#define NLOG 157   // logits tiles, 32 cols each (last tile 8 valid)
#define NGATE 80   // gate blocks: 8 units x 4 gates each
#define NB   240   // 8 barrier groups x 30

// workspace layout (float offsets)
#define O_JOINT 0        // jointT[j][b]  (640x32)   cross-block (sc1 path)
#define O_HT    20480    // hT[j][b]      (640x32)   cross-block (sc1 path)
#define O_PM    40960    // partial max    [157*32]  cross-block (sc1 path)
#define O_PS    46080    // partial sumexp [157*32]  cross-block (sc1 path)
#define O_PI    51200    // partial argmax [157*32] (int bits)    (sc1 path)
#define O_BAR   56320    // barrier: 17 slots x 32 u32 (128B padded)
#define O_CT    56960    // initial c (640x32) — consumed once at kernel start
#define O_PNT   77440    // initial out_PN (640x32) — consumed once
#define O_XWXB  97920    // embed@Wx + b  (5000x2560), optional
#define XWXB_ELEMS ((size_t)VV * (size_t)H4)
#define O_WHP   (O_XWXB + 12800000)   // repacked Wh: [80][640][32], optional
#define WHP_ELEMS ((size_t)NGATE * HH * 32)

typedef unsigned int u32;
typedef unsigned long long u64;
typedef float vf4 __attribute__((ext_vector_type(4)));  // native vector for nontemporal builtins

__device__ __forceinline__ float sigf(float x) { return 1.0f / (1.0f + expf(-x)); }

// ---- sc1 (MALL-coherent, L2-bypassing) scalar access helpers.
__device__ __forceinline__ float ldc1(const float* p) {
  u32 v = __hip_atomic_load((const u32*)p, __ATOMIC_RELAXED, __HIP_MEMORY_SCOPE_AGENT);
  return __uint_as_float(v);
}
__device__ __forceinline__ void stc1(float* p, float x) {
  __hip_atomic_store((u32*)p, __float_as_uint(x), __ATOMIC_RELAXED, __HIP_MEMORY_SCOPE_AGENT);
}

// ---- staged sc1 burst: 20480 floats (5120 float4) global -> LDS, 512 threads,
// ---- 10 dwordx4 loads per thread issued back-to-back, ONE vmcnt wait.
__device__ __forceinline__ void stage_sc1_full(float* dst, const float* src, int tid) {
  const float* p0 = src + 4 * (tid + 0 * 512);
  const float* p1 = src + 4 * (tid + 1 * 512);
  const float* p2 = src + 4 * (tid + 2 * 512);
  const float* p3 = src + 4 * (tid + 3 * 512);
  const float* p4 = src + 4 * (tid + 4 * 512);
  const float* p5 = src + 4 * (tid + 5 * 512);
  const float* p6 = src + 4 * (tid + 6 * 512);
  const float* p7 = src + 4 * (tid + 7 * 512);
  const float* p8 = src + 4 * (tid + 8 * 512);
  const float* p9 = src + 4 * (tid + 9 * 512);
  float4 a0, a1, a2, a3, a4, a5, a6, a7, a8, a9;
  asm volatile(
      "global_load_dwordx4 %0, %10, off sc0 sc1\n\t"
      "global_load_dwordx4 %1, %11, off sc0 sc1\n\t"
      "global_load_dwordx4 %2, %12, off sc0 sc1\n\t"
      "global_load_dwordx4 %3, %13, off sc0 sc1\n\t"
      "global_load_dwordx4 %4, %14, off sc0 sc1\n\t"
      "global_load_dwordx4 %5, %15, off sc0 sc1\n\t"
      "global_load_dwordx4 %6, %16, off sc0 sc1\n\t"
      "global_load_dwordx4 %7, %17, off sc0 sc1\n\t"
      "global_load_dwordx4 %8, %18, off sc0 sc1\n\t"
      "global_load_dwordx4 %9, %19, off sc0 sc1\n\t"
      "s_waitcnt vmcnt(0)"
      : "=&v"(a0), "=&v"(a1), "=&v"(a2), "=&v"(a3), "=&v"(a4),
        "=&v"(a5), "=&v"(a6), "=&v"(a7), "=&v"(a8), "=&v"(a9)
      : "v"(p0), "v"(p1), "v"(p2), "v"(p3), "v"(p4),
        "v"(p5), "v"(p6), "v"(p7), "v"(p8), "v"(p9)
      : "memory");
  float4* d4 = (float4*)dst;
  d4[tid + 0 * 512] = a0;
  d4[tid + 1 * 512] = a1;
  d4[tid + 2 * 512] = a2;
  d4[tid + 3 * 512] = a3;
  d4[tid + 4 * 512] = a4;
  d4[tid + 5 * 512] = a5;
  d4[tid + 6 * 512] = a6;
  d4[tid + 7 * 512] = a7;
  d4[tid + 8 * 512] = a8;
  d4[tid + 9 * 512] = a9;
}

// grid barrier: fence-free, monotonic no-reset counters (epoch-valued).
__device__ __forceinline__ void grid_bar(unsigned* bar, unsigned epoch) {
  __syncthreads();
  if (threadIdx.x == 0) {
    const int g = (int)blockIdx.x / 30;
    unsigned* cnt = bar + g * 32;
    unsigned* gen = bar + (9 + g) * 32;
    asm volatile("s_waitcnt vmcnt(0)" ::: "memory");
    unsigned a = __hip_atomic_fetch_add(cnt, 1u, __ATOMIC_RELAXED, __HIP_MEMORY_SCOPE_AGENT);
    if (a == 30u * epoch - 1u) {
      unsigned* root = bar + 8 * 32;
      unsigned r = __hip_atomic_fetch_add(root, 1u, __ATOMIC_RELAXED, __HIP_MEMORY_SCOPE_AGENT);
      if (r == 8u * epoch - 1u) {
#pragma unroll
        for (int i = 0; i < 8; ++i)
          __hip_atomic_store(bar + (9 + i) * 32, epoch, __ATOMIC_RELAXED, __HIP_MEMORY_SCOPE_AGENT);
      }
    }
    while (__hip_atomic_load(gen, __ATOMIC_RELAXED, __HIP_MEMORY_SCOPE_AGENT) < epoch)
      __builtin_amdgcn_s_sleep(1);
  }
  __syncthreads();
}

// ---------------- precompute: xwxb[v][c] = sum_k embed[v][k]*Wx[k][c] + b[c]
__global__ __launch_bounds__(256) void precompute_k(const float* __restrict__ embed,
                                                    const float* __restrict__ Wx,
                                                    const float* __restrict__ bias,
                                                    float* __restrict__ xwxb) {
  __shared__ float embT[HH * 17];
  const int tid = threadIdx.x;
  const int v0 = blockIdx.y * 16;
  const int c0 = blockIdx.x * 256 + (tid & 63) * 4;
  const int vg = tid >> 6;
  for (int i = tid; i < 16 * 160; i += 256) {
    int vr = i / 160, kq = i - vr * 160;
    int v = v0 + vr; if (v >= VV) v = VV - 1;
    float4 e = *(const float4*)&embed[(size_t)v * HH + kq * 4];
    embT[(kq * 4 + 0) * 17 + vr] = e.x;
    embT[(kq * 4 + 1) * 17 + vr] = e.y;
    embT[(kq * 4 + 2) * 17 + vr] = e.z;
    embT[(kq * 4 + 3) * 17 + vr] = e.w;
  }
  __syncthreads();
  float acc[16];
#pragma unroll
  for (int i = 0; i < 16; ++i) acc[i] = 0.f;
#pragma unroll 4
  for (int k = 0; k < HH; ++k) {
    float4 wv = *(const float4*)&Wx[(size_t)k * H4 + c0];
#pragma unroll
    for (int i = 0; i < 4; ++i) {
      float e = embT[k * 17 + vg * 4 + i];
      acc[i * 4 + 0] += e * wv.x;
      acc[i * 4 + 1] += e * wv.y;
      acc[i * 4 + 2] += e * wv.z;
      acc[i * 4 + 3] += e * wv.w;
    }
  }
  float4 bv = *(const float4*)&bias[c0];
#pragma unroll
  for (int i = 0; i < 4; ++i) {
    int v = v0 + vg * 4 + i;
    if (v < VV) {
      float4 r;
      r.x = acc[i * 4 + 0] + bv.x; r.y = acc[i * 4 + 1] + bv.y;
      r.z = acc[i * 4 + 2] + bv.z; r.w = acc[i * 4 + 3] + bv.w;
      *(float4*)&xwxb[(size_t)v * H4 + c0] = r;
    }
  }
}

// ---------------- repack Wh into dense per-gate-slice layout (once)
__global__ __launch_bounds__(256) void repack_k(const float* __restrict__ Wh,
                                                float* __restrict__ whp) {
  const int q = blockIdx.x;
  for (int i = threadIdx.x; i < HH * 32; i += 256) {
    int k = i >> 5, lc = i & 31;
    whp[((size_t)q * HH + k) * 32 + lc] =
        Wh[(size_t)k * H4 + (lc >> 3) * HH + q * 8 + (lc & 7)];
  }
}

// ---------------- init: barrier zero + initial LSTM step (h0=c0=0, tok=0) + joint t=0
__global__ __launch_bounds__(256) void init_k(const float* __restrict__ tn,
                                              const float* __restrict__ embed,
                                              const float* __restrict__ Wx,
                                              const float* __restrict__ bias,
                                              float* ws, int use_table) {
  const int tid = threadIdx.x, bid = blockIdx.x;
  const int b = tid & 31, c8 = tid >> 5;
  const int j = bid * 8 + c8;
  if (bid == 0) {
    unsigned* bar = (unsigned*)(ws + O_BAR);
    for (int i = tid; i < 17 * 32; i += 256) bar[i] = 0u;
  }
  const float* xwxb = ws + O_XWXB;
  float g4[4];
  if (use_table) {
#pragma unroll
    for (int g = 0; g < 4; ++g) g4[g] = xwxb[g * HH + j];  // token 0 row
  } else {
#pragma unroll
    for (int g = 0; g < 4; ++g) g4[g] = bias[g * HH + j];
#pragma unroll 4
    for (int k = 0; k < HH; ++k) {
      float xv = embed[k];  // token 0 row
#pragma unroll
      for (int g = 0; g < 4; ++g) g4[g] += xv * Wx[(size_t)k * H4 + g * HH + j];
    }
  }
  float c1 = sigf(g4[0]) * tanhf(g4[2]);
  float h1 = sigf(g4[3]) * tanhf(c1);
  ws[O_CT + j * 32 + b] = c1;
  ws[O_HT + j * 32 + b] = h1;
  ws[O_PNT + j * 32 + b] = h1;
  ws[O_JOINT + j * 32 + b] = tanhf(tn[(size_t)b * TT * HH + j] + h1);
}

// ---------------- persistent decode kernel
__global__ __launch_bounds__(512) void decode_k(const float* __restrict__ tn,
                                                const float* __restrict__ embed,
                                                const float* __restrict__ Wx,
                                                const float* __restrict__ bias,
                                                const float* __restrict__ Wh,
                                                const float* __restrict__ Wc,
                                                const float* __restrict__ bc,
                                                float* __restrict__ out,
                                                float* ws, int use_table, int use_pack) {
  __shared__ float joint_s[20480];  // 80 KB: full 640x32 joint/h tile (per step)
  __shared__ float smem[10800];     // scratch overlay: part[8][1152] / reduce / B scratch
  __shared__ float hwh_s[1056];     // gate: hwh[lc(32) stride 33][b]  (persists A->B)
  __shared__ float c_s[256];        // gate: c state (LDS-resident)
  __shared__ float pn_s[256];       // gate: out_PN state
  __shared__ int s_tok[32];
  __shared__ int s_upd[32];
  __shared__ int s_ptok[32];
  __shared__ float s_scores[32];
  const int tid = threadIdx.x, bid = blockIdx.x;
  unsigned* bar = (unsigned*)(ws + O_BAR);
  const float* xwxb = ws + O_XWXB;
  const bool is_log = (bid < NLOG);
  const bool is_gate = (bid >= NLOG) && (bid < NLOG + NGATE);
  const int q = bid - NLOG;  // gate slice index

  if (tid < 32) { s_ptok[tid] = 0; s_scores[tid] = 0.f; }
  if (is_gate && tid < 256) {
    const int jj = tid >> 5, b = tid & 31;
    c_s[jj * 32 + b] = ws[O_CT + (q * 8 + jj) * 32 + b];
    pn_s[jj * 32 + b] = ws[O_PNT + (q * 8 + jj) * 32 + b];
  }
  __syncthreads();

  // ---- GEMM thread decomposition: 8 cols x 4 batches per thread, 16-way K split
  const int lane = tid & 63, wvv = tid >> 6;
  const int sub = lane >> 5;          // K-split parity
  const int cg  = lane & 3;           // 4 col-groups of 8 cols
  const int bg  = (lane >> 2) & 7;    // 8 batch-groups of 4
  const int kb  = (wvv * 2 + sub) * 40;  // this thread's 40-row K chunk
  // weight base pointer + row stride
  const float* wbase;
  int wstride;
  if (is_log) {
    int c = bid * 32 + cg * 8;
    if (c > VV - 8) c = VV - 8;   // clamp (dup cols; masked at logits stage)
    wbase = Wc + (size_t)kb * VV + c;
    wstride = VV;
  } else if (use_pack) {
    wbase = ws + O_WHP + ((size_t)q * HH + kb) * 32 + cg * 8;  // dense 128B lines
    wstride = 32;
  } else {
    wbase = Wh + (size_t)kb * H4 + cg * HH + q * 8;
    wstride = H4;
  }
  const float* jb0 = joint_s + kb * 32 + bg * 4;

  unsigned epoch = 0;
  for (int t = 0; t < TT; ++t) {
    float tnv = 0.f;  // gate: tn[b][t+1][8q+jj], prefetched (held across barrier 1)

    // ================= phase A =================
    if (is_log || is_gate) {
      if (is_gate && tid < 256 && t + 1 < TT)
        tnv = tn[((size_t)(tid & 31) * TT + (t + 1)) * HH + q * 8 + (tid >> 5)];
      // stage the full 640x32 tile: one sc1 burst, one latency shot
      stage_sc1_full(joint_s, ws + (is_log ? O_JOINT : O_HT), tid);
      __syncthreads();

      float acc[32];  // acc[c*4+b]: 8 cols x 4 batches
#pragma unroll
      for (int i = 0; i < 32; ++i) acc[i] = 0.f;
      if (is_log) {
        const float* wp = wbase;
        const float* jp = jb0;
#pragma unroll 4
        for (int kk = 0; kk < 40; ++kk) {
          float4 w0 = *(const float4*)(wp);
          float4 w1 = *(const float4*)(wp + 4);
          float4 jv = *(const float4*)(jp);
          wp += wstride;
          jp += 32;
          acc[0]  += w0.x * jv.x; acc[1]  += w0.x * jv.y; acc[2]  += w0.x * jv.z; acc[3]  += w0.x * jv.w;
          acc[4]  += w0.y * jv.x; acc[5]  += w0.y * jv.y; acc[6]  += w0.y * jv.z; acc[7]  += w0.y * jv.w;
          acc[8]  += w0.z * jv.x; acc[9]  += w0.z * jv.y; acc[10] += w0.z * jv.z; acc[11] += w0.z * jv.w;
          acc[12] += w0.w * jv.x; acc[13] += w0.w * jv.y; acc[14] += w0.w * jv.z; acc[15] += w0.w * jv.w;
          acc[16] += w1.x * jv.x; acc[17] += w1.x * jv.y; acc[18] += w1.x * jv.z; acc[19] += w1.x * jv.w;
          acc[20] += w1.y * jv.x; acc[21] += w1.y * jv.y; acc[22] += w1.y * jv.z; acc[23] += w1.y * jv.w;
          acc[24] += w1.z * jv.x; acc[25] += w1.z * jv.y; acc[26] += w1.z * jv.z; acc[27] += w1.z * jv.w;
          acc[28] += w1.w * jv.x; acc[29] += w1.w * jv.y; acc[30] += w1.w * jv.z; acc[31] += w1.w * jv.w;
        }
      } else {
        // gate: weight stream is single-use per step -> non-temporal (no L2 pollution)
        const float* wp = wbase;
        const float* jp = jb0;
#pragma unroll 4
        for (int kk = 0; kk < 40; ++kk) {
          vf4 w0 = __builtin_nontemporal_load((const vf4*)(wp));
          vf4 w1 = __builtin_nontemporal_load((const vf4*)(wp + 4));
          float4 jv = *(const float4*)(jp);
          wp += wstride;
          jp += 32;
          acc[0]  += w0.x * jv.x; acc[1]  += w0.x * jv.y; acc[2]  += w0.x * jv.z; acc[3]  += w0.x * jv.w;
          acc[4]  += w0.y * jv.x; acc[5]  += w0.y * jv.y; acc[6]  += w0.y * jv.z; acc[7]  += w0.y * jv.w;
          acc[8]  += w0.z * jv.x; acc[9]  += w0.z * jv.y; acc[10] += w0.z * jv.z; acc[11] += w0.z * jv.w;
          acc[12] += w0.w * jv.x; acc[13] += w0.w * jv.y; acc[14] += w0.w * jv.z; acc[15] += w0.w * jv.w;
          acc[16] += w1.x * jv.x; acc[17] += w1.x * jv.y; acc[18] += w1.x * jv.z; acc[19] += w1.x * jv.w;
          acc[20] += w1.y * jv.x; acc[21] += w1.y * jv.y; acc[22] += w1.y * jv.z; acc[23] += w1.y * jv.w;
          acc[24] += w1.z * jv.x; acc[25] += w1.z * jv.y; acc[26] += w1.z * jv.z; acc[27] += w1.z * jv.w;
          acc[28] += w1.w * jv.x; acc[29] += w1.w * jv.y; acc[30] += w1.w * jv.z; acc[31] += w1.w * jv.w;
        }
      }
      // combine K-split pairs (sub 0/1) within the wave
#pragma unroll
      for (int i = 0; i < 32; ++i) acc[i] += __shfl_xor(acc[i], 32);
      float* part = smem;  // [8 waves][32 cols * 36]
      if (sub == 0) {
        float* pb = part + wvv * 1152 + bg * 4;
#pragma unroll
        for (int c = 0; c < 8; ++c)
          *(float4*)&pb[(cg * 8 + c) * 36] =
              make_float4(acc[c * 4 + 0], acc[c * 4 + 1], acc[c * 4 + 2], acc[c * 4 + 3]);
      }
      __syncthreads();

      const int b = tid & 31, colg = tid >> 5;
      if (is_log) {
        float* lm = smem + 9216;
        float* lsv = smem + 9744;
        int* lix = (int*)(smem + 10272);
        float m = -FLT_MAX; int ix = 0;
        float lv[2];
#pragma unroll
        for (int i = 0; i < 2; ++i) {
          const int cl = colg * 2 + i;
          float s = 0.f;
#pragma unroll
          for (int qq = 0; qq < 8; ++qq) s += part[qq * 1152 + cl * 36 + b];
          int cgl = bid * 32 + cl;
          float l = (cgl < VV) ? s + bc[cgl] : -FLT_MAX;
          lv[i] = l;
          if (l > m) { m = l; ix = cgl; }
        }
        float e = 0.f;
        if (m > -FLT_MAX) {
#pragma unroll
          for (int i = 0; i < 2; ++i) e += expf(lv[i] - m);
        }
        lm[colg * 33 + b] = m; lsv[colg * 33 + b] = e; lix[colg * 33 + b] = ix;
        __syncthreads();
        if (tid < 32) {
          float m2 = lm[tid], s2 = lsv[tid]; int ix2 = lix[tid];
#pragma unroll
          for (int qq = 1; qq < 16; ++qq) {
            float M = lm[qq * 33 + tid], S = lsv[qq * 33 + tid]; int I = lix[qq * 33 + tid];
            if (M > m2) { s2 = s2 * expf(m2 - M) + S; m2 = M; ix2 = I; }
            else if (M > -FLT_MAX) { s2 += S * expf(M - m2); }
          }
          stc1(&ws[O_PM + bid * 32 + tid], m2);                    // sc1 write-through
          stc1(&ws[O_PS + bid * 32 + tid], s2);
          stc1(&ws[O_PI + bid * 32 + tid], __int_as_float(ix2));
        }
      } else {
#pragma unroll
        for (int i = 0; i < 2; ++i) {
          const int cl = colg * 2 + i;
          float s = 0.f;
#pragma unroll
          for (int qq = 0; qq < 8; ++qq) s += part[qq * 1152 + cl * 36 + b];
          hwh_s[cl * 33 + b] = s;  // stays in LDS — no global round-trip
        }
      }
    }
    epoch++;
    grid_bar(bar, epoch);  // gate blocks read partials next

    // ================= phase B (gate blocks only) =================
    if (is_gate) {
      float* rm = smem;               // [16*33]
      float* rs = smem + 528;
      int* ri = (int*)(smem + 1056);
      float* gmat = smem + 1584;      // [32*33]
      float* xl = smem + 2640;        // [32*161] fallback staging
      const int r = tid & 31, c16 = tid >> 5;
      {
        // hoisted gather: all 30 sc1 loads issued before the combine (1 shot)
        float Ms[10], Ss[10]; int Is[10];
#pragma unroll
        for (int i = 0; i < 10; ++i) {
          int idx = c16 * 10 + i;
          bool v = (idx < NLOG);
          int ic = v ? idx : 0;
          Ms[i] = ldc1(&ws[O_PM + ic * 32 + r]);
          Ss[i] = ldc1(&ws[O_PS + ic * 32 + r]);
          Is[i] = __float_as_int(ldc1(&ws[O_PI + ic * 32 + r]));
          if (!v) { Ms[i] = -FLT_MAX; Ss[i] = 0.f; Is[i] = 0; }
        }
        float m = -FLT_MAX, s = 0.f; int ix = 0;
#pragma unroll
        for (int i = 0; i < 10; ++i) {
          if (Ms[i] > m) { s = s * expf(m - Ms[i]) + Ss[i]; m = Ms[i]; ix = Is[i]; }
          else if (Ms[i] > -FLT_MAX) { s += Ss[i] * expf(Ms[i] - m); }
        }
        rm[c16 * 33 + r] = m; rs[c16 * 33 + r] = s; ri[c16 * 33 + r] = ix;
      }
      __syncthreads();
      if (tid < 32) {
        float m = rm[tid], s = rs[tid]; int ix = ri[tid];
#pragma unroll
        for (int qq = 1; qq < 16; ++qq) {
          float M = rm[qq * 33 + tid], S = rs[qq * 33 + tid]; int I = ri[qq * 33 + tid];
          if (M > m) { s = s * expf(m - M) + S; m = M; ix = I; }
          else { s += S * expf(M - m); }
        }
        int pos = ix;
        int upd = (pos != 0) ? 1 : 0;
        int ntk = upd ? pos : s_ptok[tid];
        s_tok[tid] = ntk; s_upd[tid] = upd; s_ptok[tid] = ntk;
        if (bid == NLOG) {  // emitter
          float sc = s_scores[tid];
          if (upd) sc -= logf(s);
          s_scores[tid] = sc;
          out[BB + (size_t)tid * TT + t] = upd ? (float)pos : 0.0f;
          if (t == TT - 1) out[tid] = sc;
        }
      }
      __syncthreads();

      // gate pre-activations for the block's 32 strided cols
      const int b = tid & 31;
      float gv[2];
#pragma unroll
      for (int h = 0; h < 2; ++h) {
        int lc = (tid >> 5) + h * 16;
        int wcol = (lc >> 3) * HH + q * 8 + (lc & 7);
        float v = hwh_s[lc * 33 + b];
        if (use_table) v += __builtin_nontemporal_load(&xwxb[(size_t)s_tok[b] * H4 + wcol]);
        else v += bias[wcol];
        gv[h] = v;
      }
      if (!use_table) {
        for (int st = 0; st < 4; ++st) {
          const int k0 = st * 160;
          __syncthreads();
          for (int i = tid; i < 32 * 160; i += 512) {
            int bb = i / 160, kk = i - bb * 160;
            xl[bb * 161 + kk] = embed[(size_t)s_tok[bb] * HH + k0 + kk];
          }
          __syncthreads();
          for (int k = 0; k < 160; ++k) {
            float xv = xl[b * 161 + k];
#pragma unroll
            for (int h = 0; h < 2; ++h) {
              int lc = (tid >> 5) + h * 16;
              int wcol = (lc >> 3) * HH + q * 8 + (lc & 7);
              gv[h] += xv * Wx[(size_t)(k0 + k) * H4 + wcol];
            }
          }
        }
      }
#pragma unroll
      for (int h = 0; h < 2; ++h) {
        int lc = (tid >> 5) + h * 16;
        gmat[lc * 33 + b] = gv[h];
      }
      __syncthreads();
      if (tid < 256) {
        const int jj = tid >> 5, b2 = tid & 31;
        float gi = gmat[(0 * 8 + jj) * 33 + b2];
        float gf = gmat[(1 * 8 + jj) * 33 + b2];
        float gg = gmat[(2 * 8 + jj) * 33 + b2];
        float go = gmat[(3 * 8 + jj) * 33 + b2];
        float cold = c_s[jj * 32 + b2];
        float c2 = sigf(gf) * cold + sigf(gi) * tanhf(gg);
        float h2 = sigf(go) * tanhf(c2);
        float pv;
        if (s_upd[b2]) {
          c_s[jj * 32 + b2] = c2;
          pn_s[jj * 32 + b2] = h2;
          stc1(&ws[O_HT + (q * 8 + jj) * 32 + b2], h2);   // sc1 write-through
          pv = h2;
        } else {
          pv = pn_s[jj * 32 + b2];
        }
        if (t + 1 < TT)
          stc1(&ws[O_JOINT + (q * 8 + jj) * 32 + b2], tanhf(tnv + pv));  // sc1
      }
    }
    epoch++;
    grid_bar(bar, epoch);  // next A stages jointT / hT
  }
}

extern "C" void kernel_launch(void* const* d_in, const int* in_sizes, int n_in,
                              void* d_out, int out_size, void* d_ws, size_t ws_size,
                              hipStream_t stream) {
  const float* tn    = (const float*)d_in[0];
  const float* embed = (const float*)d_in[1];
  const float* Wx    = (const float*)d_in[2];
  const float* Wh    = (const float*)d_in[3];
  const float* bias  = (const float*)d_in[4];
  const float* Wc    = (const float*)d_in[5];
  const float* bc    = (const float*)d_in[6];
  float* out = (float*)d_out;
  float* ws  = (float*)d_ws;

  const size_t need_table = (size_t)(O_XWXB + XWXB_ELEMS) * sizeof(float);
  const size_t need_pack  = (size_t)(O_WHP + WHP_ELEMS) * sizeof(float);
  const int use_table = (ws_size >= need_table) ? 1 : 0;
  const int use_pack  = (ws_size >= need_pack) ? 1 : 0;

  if (use_table)
    hipLaunchKernelGGL(precompute_k, dim3(10, 313), dim3(256), 0, stream,
                       embed, Wx, bias, ws + O_XWXB);
  if (use_pack)
    hipLaunchKernelGGL(repack_k, dim3(NGATE), dim3(256), 0, stream, Wh, ws + O_WHP);
  hipLaunchKernelGGL(init_k, dim3(80), dim3(256), 0, stream, tn, embed, Wx, bias, ws, use_table);
  hipLaunchKernelGGL(decode_k, dim3(NB), dim3(512), 0, stream,
                     tn, embed, Wx, bias, Wh, Wc, bc, out, ws, use_table, use_pack);
}